// Round 6
// baseline (6513.853 us; speedup 1.0000x reference)
//
#include <hip/hip_runtime.h>
#include <cstddef>

#define Bv   32
#define Sv   197
#define Dv   768
#define Hh   12
#define HDv  64
#define Fv   3072
#define Lv   12
#define Ov   512
#define TOK  (Bv * Sv)        // 6304
#define MPAD 6400             // TOK padded (multiple of 128: 50*128)
#define NPATCH 196
#define CONV_M (Bv * NPATCH)  // 6272

#define WQ_SZ (2304 * 768)
#define WO_SZ (768 * 768)
#define WF_SZ (3072 * 768)
#define WP_SZ (768 * 3072)
#define WTOT  (WQ_SZ + WO_SZ + WF_SZ + WP_SZ)   // 7077888

typedef __attribute__((ext_vector_type(8))) __bf16 bf16x8;
typedef __attribute__((ext_vector_type(4))) float f32x4;

__device__ __forceinline__ unsigned short f2bf(float f) {
    unsigned int u = __float_as_uint(f);
    unsigned int r = (u + 0x7fffu + ((u >> 16) & 1u)) >> 16;
    return (unsigned short)r;
}

// ---------------------------------------------------------------------------
// block-wide (256 thread) reduction of two scalars
// ---------------------------------------------------------------------------
__device__ __forceinline__ void reduce2_256(float& s1, float& s2) {
    #pragma unroll
    for (int off = 32; off > 0; off >>= 1) {
        s1 += __shfl_down(s1, off, 64);
        s2 += __shfl_down(s2, off, 64);
    }
    __shared__ float r1[4], r2[4];
    int lane = threadIdx.x & 63, w = threadIdx.x >> 6;
    if (lane == 0) { r1[w] = s1; r2[w] = s2; }
    __syncthreads();
    s1 = r1[0] + r1[1] + r1[2] + r1[3];
    s2 = r2[0] + r2[1] + r2[2] + r2[3];
    __syncthreads();
}

// ---------------------------------------------------------------------------
// weight fp32 -> bf16 conversion
// ---------------------------------------------------------------------------
__global__ void convert_kernel(const float* __restrict__ src,
                               unsigned short* __restrict__ dst, int n4) {
    int gid = blockIdx.x * 256 + threadIdx.x;
    if (gid >= n4) return;
    int idx = gid * 4;
    float4 v = *(const float4*)(src + idx);
    ushort4 r = make_ushort4(f2bf(v.x), f2bf(v.y), f2bf(v.z), f2bf(v.w));
    *(ushort4*)(dst + idx) = r;
}

__global__ void convertw_kernel(const float* __restrict__ wq,
                                const float* __restrict__ wo,
                                const float* __restrict__ wf,
                                const float* __restrict__ wp,
                                unsigned short* __restrict__ dst) {
    int idx = (blockIdx.x * 256 + threadIdx.x) * 4;
    const float* s; int off;
    if (idx < WQ_SZ)                     { s = wq; off = idx; }
    else if (idx < WQ_SZ + WO_SZ)        { s = wo; off = idx - WQ_SZ; }
    else if (idx < WQ_SZ + WO_SZ + WF_SZ){ s = wf; off = idx - WQ_SZ - WO_SZ; }
    else                                 { s = wp; off = idx - WQ_SZ - WO_SZ - WF_SZ; }
    float4 v = *(const float4*)(s + off);
    ushort4 r = make_ushort4(f2bf(v.x), f2bf(v.y), f2bf(v.z), f2bf(v.w));
    *(ushort4*)(dst + idx) = r;
}

// ---------------------------------------------------------------------------
// im2col + normalize -> bf16 patches [6272, 768]
// ---------------------------------------------------------------------------
__global__ void im2col_kernel(const float* __restrict__ img,
                              unsigned short* __restrict__ out) {
    int idx = blockIdx.x * 256 + threadIdx.x;
    int col = idx % 768;
    int row = idx / 768;
    int b = row / NPATCH, p = row % NPATCH;
    int ph = p / 14, pw = p % 14;
    int c  = col >> 8;
    int r  = col & 255;
    int kh = r >> 4, kw = r & 15;
    int y = ph * 16 + kh, x = pw * 16 + kw;
    const float mean[3] = {0.48145466f, 0.4578275f, 0.40821073f};
    const float stdv[3] = {0.26862954f, 0.26130258f, 0.27577711f};
    float v = img[((size_t)(b * 3 + c) * 224 + y) * 224 + x];
    out[idx] = f2bf((v - mean[c]) / stdv[c]);
}

// ---------------------------------------------------------------------------
// MFMA bf16 GEMM: C[m,n] = sum_k A[m,k]*W[n,k] (+bias) (+res fp32) (QuickGELU)
// v7: 128x128 tile, BK=64, 256 threads (4 waves = 2M x 2N, each 64x64).
//  - REGISTER-STAGED double buffer (T14): global->VGPR loads for tile t+1
//    issued BEFORE compute(t) (full compute phase of latency cover, wait is
//    compiler-inserted + covered); ds_write to the idle buffer needs no
//    inter-wave wait; ONE barrier per K-iter. No global_load_lds, no
//    vmcnt(0)-before-barrier DMA drain (the r0-r5 invariant serial chain).
//  - XOR swizzle now applied on the ds_write side (linear coalesced global
//    reads) + same swizzled ds_read -> conflict-free as verified (r3: 0).
//  - split-K via gridDim.z: ODT==2 accumulates with fp32 atomicAdd into C
//    (C pre-holds residual; bias added by the z==0 block only).
//  - XCD-aware bijective workgroup remap kept.
// ---------------------------------------------------------------------------
template<int ODT, int ACT>
__global__ __launch_bounds__(256) void gemm_mfma(
        const unsigned short* __restrict__ A, const unsigned short* __restrict__ W,
        const float* __restrict__ bias, const float* __restrict__ res,
        void* __restrict__ Cv, int M, int N, int K)
{
    __shared__ unsigned short As[2][128 * 64];   // 2 x 16 KB
    __shared__ unsigned short Ws[2][128 * 64];   // 2 x 16 KB
    const int tid = threadIdx.x;
    const int w = tid >> 6, l = tid & 63;

    // ---- XCD-aware bijective remap of linear workgroup id (T1, m204) ----
    const int gx = gridDim.x;
    const int wg  = blockIdx.y * gx + blockIdx.x;
    const int nwg = gx * gridDim.y;
    const int q = nwg >> 3, r8 = nwg & 7;
    const int xcd = wg & 7, lo = wg >> 3;
    const int swz = (xcd < r8 ? xcd * (q + 1) : r8 * (q + 1) + (xcd - r8) * q) + lo;
    const int m0 = (swz / gx) << 7;      // 128-row tile
    const int n0 = (swz % gx) << 7;      // 128-col tile

    // ---- split-K ----
    const int kseg  = K / gridDim.z;
    const int kbase = blockIdx.z * kseg;

    // ---- staging: LINEAR global source; swizzle applied at ds_write ----
    // wave w covers 32 rows (w*32 .. w*32+31); per load instr: 8 rows x 8
    // chunks of 16B. lane l -> row lrow = l>>3, chunk = l&7.
    const int lrow = l >> 3;
    const int chk  = l & 7;
    const unsigned short* agp = A + (size_t)(m0 + w * 32 + lrow) * K + kbase + chk * 8;
    const unsigned short* wgp = W + (size_t)(n0 + w * 32 + lrow) * K + kbase + chk * 8;
    // swizzled LDS write offset (shorts): row R = w*32 + i*8 + lrow,
    // chunk' = chk ^ (R & 7) = chk ^ lrow  (i*8, w*32 are 0 mod 8)
    const int wds = (w * 32 + lrow) * 64 + ((chk ^ lrow) * 8);

    // ---- fragment read offsets (swizzled, same key: chunk ^ (row&7)) ----
    const int wm = w >> 1, wn = w & 1;   // 2 x 2 waves
    const int fr = l & 15, fq = l >> 4;
    int aoff[2][4], woff[2][4];
    #pragma unroll
    for (int ks = 0; ks < 2; ks++) {
        const int pc = ((ks * 4 + fq) ^ (fr & 7)) * 8;
        #pragma unroll
        for (int i = 0; i < 4; i++) {
            aoff[ks][i] = (wm * 64 + i * 16 + fr) * 64 + pc;
            woff[ks][i] = (wn * 64 + i * 16 + fr) * 64 + pc;
        }
    }

    f32x4 acc[4][4] = {};
    const int nt = kseg >> 6;   // BK=64

    uint4 ar[4], wr[4];

    #define GLOAD(t) do {                                                  \
        const int _ko = (t) << 6;                                          \
        _Pragma("unroll")                                                  \
        for (int _i = 0; _i < 4; _i++) {                                   \
            ar[_i] = *(const uint4*)(agp + (size_t)_i * 8 * K + _ko);      \
            wr[_i] = *(const uint4*)(wgp + (size_t)_i * 8 * K + _ko);      \
        }                                                                  \
    } while (0)

    #define DSWRITE(bf) do {                                               \
        _Pragma("unroll")                                                  \
        for (int _i = 0; _i < 4; _i++) {                                   \
            *(uint4*)&As[bf][wds + _i * 512] = ar[_i];                     \
            *(uint4*)&Ws[bf][wds + _i * 512] = wr[_i];                     \
        }                                                                  \
    } while (0)

    auto compute = [&](const unsigned short* ab, const unsigned short* wb) {
        #pragma unroll
        for (int ks = 0; ks < 2; ks++) {
            bf16x8 af[4], wf[4];
            #pragma unroll
            for (int i = 0; i < 4; i++) {
                af[i] = *(const bf16x8*)(ab + aoff[ks][i]);
                wf[i] = *(const bf16x8*)(wb + woff[ks][i]);
            }
            #pragma unroll
            for (int i = 0; i < 4; i++) {
                #pragma unroll
                for (int j = 0; j < 4; j++) {
                    acc[i][j] = __builtin_amdgcn_mfma_f32_16x16x32_bf16(
                        af[i], wf[j], acc[i][j], 0, 0, 0);
                }
            }
        }
    };

    // prologue: tile 0 through regs into buf 0
    GLOAD(0);
    DSWRITE(0);
    __syncthreads();

    int bf = 0;
    for (int t = 0; t < nt; t++) {
        if (t + 1 < nt) GLOAD(t + 1);       // issued early; consumed after compute
        compute(As[bf], Ws[bf]);
        if (t + 1 < nt) {
            DSWRITE(bf ^ 1);                // idle buffer: no inter-wave wait needed
            __syncthreads();                // writes visible; reads of bf done
            bf ^= 1;
        }
    }
    #undef GLOAD
    #undef DSWRITE

    const bool addb = (ODT != 2) || (blockIdx.z == 0);
    float bn[4];
    #pragma unroll
    for (int j = 0; j < 4; j++)
        bn[j] = (bias && addb) ? bias[n0 + wn * 64 + j * 16 + fr] : 0.f;

    #pragma unroll
    for (int i = 0; i < 4; i++) {
        #pragma unroll
        for (int r = 0; r < 4; r++) {
            int m = m0 + wm * 64 + i * 16 + fq * 4 + r;
            if (m < M) {
                size_t rowb = (size_t)m * N;
                #pragma unroll
                for (int j = 0; j < 4; j++) {
                    int n = n0 + wn * 64 + j * 16 + fr;
                    float v = acc[i][j][r] + bn[j];
                    if (ODT == 2) {
                        atomicAdd((float*)Cv + rowb + n, v);
                    } else {
                        if (res) v += res[rowb + n];
                        if (ACT) v = v / (1.f + __expf(-1.702f * v));
                        if (ODT == 0) ((float*)Cv)[rowb + n] = v;
                        else ((unsigned short*)Cv)[rowb + n] = f2bf(v);
                    }
                }
            }
        }
    }
}

// ---------------------------------------------------------------------------
// LayerNorm fp32 in -> bf16 out. One block per token.
// ---------------------------------------------------------------------------
__global__ void ln_kernel(const float* __restrict__ in, unsigned short* __restrict__ out,
                          const float* __restrict__ s, const float* __restrict__ b) {
    int t = blockIdx.x;
    const float* row = in + (size_t)t * Dv;
    int tid = threadIdx.x;
    float v[3], s1 = 0.f, s2 = 0.f;
    #pragma unroll
    for (int i = 0; i < 3; i++) {
        v[i] = row[tid + 256 * i];
        s1 += v[i]; s2 += v[i] * v[i];
    }
    reduce2_256(s1, s2);
    float mean = s1 * (1.0f / Dv);
    float var  = s2 * (1.0f / Dv) - mean * mean;
    float rstd = rsqrtf(var + 1e-5f);
    unsigned short* orow = out + (size_t)t * Dv;
    #pragma unroll
    for (int i = 0; i < 3; i++) {
        int d = tid + 256 * i;
        orow[d] = f2bf((v[i] - mean) * rstd * s[d] + b[d]);
    }
}

// ---------------------------------------------------------------------------
// embed (cls/patch + pos) + ln_pre -> x fp32. One block per token.
// ---------------------------------------------------------------------------
__global__ void embed_ln_kernel(const float* __restrict__ conv_out,
                                const float* __restrict__ cls,
                                const float* __restrict__ pos,
                                const float* __restrict__ s,
                                const float* __restrict__ b,
                                float* __restrict__ x) {
    int t = blockIdx.x;
    int bb = t / Sv, si = t % Sv;
    int tid = threadIdx.x;
    float v[3], s1 = 0.f, s2 = 0.f;
    #pragma unroll
    for (int i = 0; i < 3; i++) {
        int d = tid + 256 * i;
        float e = (si == 0) ? cls[d]
                            : conv_out[((size_t)bb * NPATCH + (si - 1)) * Dv + d];
        v[i] = e + pos[(size_t)si * Dv + d];
        s1 += v[i]; s2 += v[i] * v[i];
    }
    reduce2_256(s1, s2);
    float mean = s1 * (1.0f / Dv);
    float var  = s2 * (1.0f / Dv) - mean * mean;
    float rstd = rsqrtf(var + 1e-5f);
    float* orow = x + (size_t)t * Dv;
    #pragma unroll
    for (int i = 0; i < 3; i++) {
        int d = tid + 256 * i;
        orow[d] = (v[i] - mean) * rstd * s[d] + b[d];
    }
}

// ---------------------------------------------------------------------------
// Attention v4 (MFMA): grid (7, H, B); block = 256 thr = 4 waves; 32 q-rows.
// ---------------------------------------------------------------------------
__global__ __launch_bounds__(256) void attn4_kernel(
        const unsigned short* __restrict__ qkv, unsigned short* __restrict__ o) {
    const int qg = blockIdx.x, h = blockIdx.y, b = blockIdx.z;
    __shared__ __align__(16) unsigned short vt[64][232];   // V^T [d][j], 29.7 KB
    __shared__ __align__(16) unsigned short pb[32][236];   // P bf16 [row][k], 14.8 KB
    __shared__ float red[4][32];
    __shared__ float smax_f[32];
    __shared__ float sinv_f[32];

    const int tid = threadIdx.x;
    const int w = tid >> 6, l = tid & 63;
    const int fr = l & 15, fq = l >> 4;
    const size_t base = (size_t)b * Sv;
    const unsigned int* q32 = (const unsigned int*)qkv;    // row stride 1152 uints

    // ---- stage V^T (cols >= 197 zeroed) ----
    for (int i = tid; i < 224 * 32; i += 256) {
        int j = i >> 5, u = i & 31;
        unsigned int val = (j < Sv) ? q32[(base + j) * 1152 + 768 + h * 32 + u] : 0u;
        vt[2 * u][j]     = (unsigned short)(val & 0xffffu);
        vt[2 * u + 1][j] = (unsigned short)(val >> 16);
    }

    union U { uint4 u; bf16x8 v; };

    // ---- QK^T: sc[mt][s], rows qg*32+mt*16+fq*4+r, cols (w+4s)*16+fr ----
    f32x4 sc[2][4] = {};
    #pragma unroll
    for (int ks = 0; ks < 2; ks++) {
        U aq[2];
        #pragma unroll
        for (int mt = 0; mt < 2; mt++) {
            int row = qg * 32 + mt * 16 + fr;
            int rc = row < Sv ? row : Sv - 1;
            aq[mt].u = *(const uint4*)(qkv + (base + rc) * 2304 + h * 64 + ks * 32 + fq * 8);
        }
        #pragma unroll
        for (int s = 0; s < 4; s++) {
            int nt = w + 4 * s;
            if (nt >= 14) continue;
            int col = nt * 16 + fr;
            int cc = col < Sv ? col : Sv - 1;
            U bq;
            bq.u = *(const uint4*)(qkv + (base + cc) * 2304 + 768 + h * 64 + ks * 32 + fq * 8);
            #pragma unroll
            for (int mt = 0; mt < 2; mt++)
                sc[mt][s] = __builtin_amdgcn_mfma_f32_16x16x32_bf16(
                    aq[mt].v, bq.v, sc[mt][s], 0, 0, 0);
        }
    }

    // ---- scale + mask + row max ----
    float rmax[2][4];
    #pragma unroll
    for (int mt = 0; mt < 2; mt++)
        #pragma unroll
        for (int r = 0; r < 4; r++) rmax[mt][r] = -1e30f;
    #pragma unroll
    for (int mt = 0; mt < 2; mt++) {
        #pragma unroll
        for (int s = 0; s < 4; s++) {
            int nt = w + 4 * s;
            int col = nt * 16 + fr;
            bool valid = (nt < 14) && (col < Sv);
            #pragma unroll
            for (int r = 0; r < 4; r++) {
                float v = valid ? sc[mt][s][r] * 0.125f : -1e30f;
                sc[mt][s][r] = v;
                rmax[mt][r] = fmaxf(rmax[mt][r], v);
            }
        }
    }
    #pragma unroll
    for (int mt = 0; mt < 2; mt++) {
        #pragma unroll
        for (int r = 0; r < 4; r++) {
            float m = rmax[mt][r];
            m = fmaxf(m, __shfl_xor(m, 1, 64));
            m = fmaxf(m, __shfl_xor(m, 2, 64));
            m = fmaxf(m, __shfl_xor(m, 4, 64));
            m = fmaxf(m, __shfl_xor(m, 8, 64));
            rmax[mt][r] = m;
        }
    }
    if (fr == 0) {
        #pragma unroll
        for (int mt = 0; mt < 2; mt++)
            #pragma unroll
            for (int r = 0; r < 4; r++)
                red[w][mt * 16 + fq * 4 + r] = rmax[mt][r];
    }
    __syncthreads();
    if (tid < 32)
        smax_f[tid] = fmaxf(fmaxf(red[0][tid], red[1][tid]),
                            fmaxf(red[2][tid], red[3][tid]));
    __syncthreads();

    // ---- exp + row sum + write P (bf16, A layout) ----
    float rsum[2][4] = {};
    #pragma unroll
    for (int mt = 0; mt < 2; mt++) {
        float fm[4];
        #pragma unroll
        for (int r = 0; r < 4; r++) fm[r] = smax_f[mt * 16 + fq * 4 + r];
        #pragma unroll
        for (int s = 0; s < 4; s++) {
            int nt = w + 4 * s;
            if (nt >= 14) continue;
            int col = nt * 16 + fr;
            #pragma unroll
            for (int r = 0; r < 4; r++) {
                float p = (col < Sv) ? __expf(sc[mt][s][r] - fm[r]) : 0.f;
                rsum[mt][r] += p;
                pb[mt * 16 + fq * 4 + r][col] = f2bf(p);
            }
        }
    }
    #pragma unroll
    for (int mt = 0; mt < 2; mt++) {
        #pragma unroll
        for (int r = 0; r < 4; r++) {
            float s = rsum[mt][r];
            s += __shfl_xor(s, 1, 64);
            s += __shfl_xor(s, 2, 64);
            s += __shfl_xor(s, 4, 64);
            s += __shfl_xor(s, 8, 64);
            rsum[mt][r] = s;
        }
    }
    if (fr == 0) {
        #pragma unroll
        for (int mt = 0; mt < 2; mt++)
            #pragma unroll
            for (int r = 0; r < 4; r++)
                red[w][mt * 16 + fq * 4 + r] = rsum[mt][r];
    }
    __syncthreads();
    if (tid < 32)
        sinv_f[tid] = 1.f / (red[0][tid] + red[1][tid] + red[2][tid] + red[3][tid]);
    __syncthreads();   // also guarantees vt + pb staging complete

    // ---- PV: wave w -> output dims [w*16, w*16+16) ----
    f32x4 oc[2] = {};
    #pragma unroll
    for (int ks = 0; ks < 7; ks++) {
        U bv;
        bv.u = *(const uint4*)&vt[w * 16 + fr][ks * 32 + fq * 8];
        #pragma unroll
        for (int mt = 0; mt < 2; mt++) {
            const unsigned short* ap = &pb[mt * 16 + fr][ks * 32 + fq * 8];
            uint2 lo = *(const uint2*)ap;
            uint2 hi = *(const uint2*)(ap + 4);
            U a; a.u = make_uint4(lo.x, lo.y, hi.x, hi.y);
            oc[mt] = __builtin_amdgcn_mfma_f32_16x16x32_bf16(a.v, bv.v, oc[mt], 0, 0, 0);
        }
    }

    // ---- epilogue: /= rowsum, store bf16 ----
    #pragma unroll
    for (int mt = 0; mt < 2; mt++) {
        #pragma unroll
        for (int r = 0; r < 4; r++) {
            int lrow = mt * 16 + fq * 4 + r;
            int row = qg * 32 + lrow;
            if (row < Sv)
                o[(base + row) * Dv + h * 64 + w * 16 + fr] =
                    f2bf(oc[mt][r] * sinv_f[lrow]);
        }
    }
}

// ---------------------------------------------------------------------------
// Head: ln_post on cls token + @ vis_proj [768,512] fp32. One block per batch.
// ---------------------------------------------------------------------------
__global__ void head_kernel(const float* __restrict__ x,
                            const float* __restrict__ s, const float* __restrict__ b,
                            const float* __restrict__ vp, float* __restrict__ out) {
    int bb = blockIdx.x, tid = threadIdx.x;
    __shared__ float xn[Dv];
    const float* row = x + (size_t)(bb * Sv) * Dv;
    float v[3], s1 = 0.f, s2 = 0.f;
    #pragma unroll
    for (int i = 0; i < 3; i++) {
        v[i] = row[tid + 256 * i];
        s1 += v[i]; s2 += v[i] * v[i];
    }
    reduce2_256(s1, s2);
    float mean = s1 * (1.0f / Dv);
    float var  = s2 * (1.0f / Dv) - mean * mean;
    float rstd = rsqrtf(var + 1e-5f);
    #pragma unroll
    for (int i = 0; i < 3; i++) {
        int d = tid + 256 * i;
        xn[d] = (v[i] - mean) * rstd * s[d] + b[d];
    }
    __syncthreads();
    float acc0 = 0.f, acc1 = 0.f;
    for (int d = 0; d < Dv; d++) {
        float xv = xn[d];
        acc0 += xv * vp[(size_t)d * Ov + tid];
        acc1 += xv * vp[(size_t)d * Ov + tid + 256];
    }
    out[(size_t)bb * Ov + tid]       = acc0;
    out[(size_t)bb * Ov + tid + 256] = acc1;
}

// ---------------------------------------------------------------------------
extern "C" void kernel_launch(void* const* d_in, const int* in_sizes, int n_in,
                              void* d_out, int out_size, void* d_ws, size_t ws_size,
                              hipStream_t stream) {
    const float* images   = (const float*)d_in[0];
    const float* conv_w   = (const float*)d_in[1];
    const float* cls_emb  = (const float*)d_in[2];
    const float* pos_emb  = (const float*)d_in[3];
    const float* lnpre_s  = (const float*)d_in[4];
    const float* lnpre_b  = (const float*)d_in[5];
    const float* ln1_s    = (const float*)d_in[6];
    const float* ln1_b    = (const float*)d_in[7];
    const float* qkv_w    = (const float*)d_in[8];
    const float* qkv_b    = (const float*)d_in[9];
    const float* out_w    = (const float*)d_in[10];
    const float* out_b    = (const float*)d_in[11];
    const float* ln2_s    = (const float*)d_in[12];
    const float* ln2_b    = (const float*)d_in[13];
    const float* fc_w     = (const float*)d_in[14];
    const float* fc_b     = (const float*)d_in[15];
    const float* proj_w   = (const float*)d_in[16];
    const float* proj_b   = (const float*)d_in[17];
    const float* lnpost_s = (const float*)d_in[18];
    const float* lnpost_b = (const float*)d_in[19];
    const float* vis_proj = (const float*)d_in[20];
    float* out = (float*)d_out;

    char* p = (char*)d_ws;
    float* x              = (float*)p;          p += (size_t)TOK * Dv * 4;       // 19.4 MB
    unsigned short* abuf  = (unsigned short*)p; p += (size_t)MPAD * Dv * 2;      //  9.8 MB
    unsigned short* qkvb  = (unsigned short*)p; p += (size_t)MPAD * 2304 * 2;    // 29.5 MB
    unsigned short* hbuf  = (unsigned short*)p; p += (size_t)MPAD * Fv * 2;      // 39.3 MB
    unsigned short* wbuf  = (unsigned short*)p; p += (size_t)WTOT * 2;           // 14.2 MB
    unsigned short* cwb   = (unsigned short*)p; p += (size_t)WO_SZ * 2;          //  1.2 MB
    // aliases (pre-loop only):
    unsigned short* im2c  = qkvb;               // [6272,768] bf16 (rows to 6400 readable)
    float* convo          = (float*)hbuf;       // [6272,768] fp32

    const int GY = MPAD / 128;   // 50 row-tiles

    // patch embedding
    convert_kernel<<<WO_SZ / 4 / 256, 256, 0, stream>>>(conv_w, cwb, WO_SZ / 4);
    im2col_kernel<<<(CONV_M * Dv) / 256, 256, 0, stream>>>(images, im2c);
    gemm_mfma<0, 0><<<dim3(Dv / 128, GY, 1), 256, 0, stream>>>(
        im2c, cwb, nullptr, nullptr, convo, CONV_M, Dv, Dv);
    embed_ln_kernel<<<TOK, 256, 0, stream>>>(convo, cls_emb, pos_emb,
                                             lnpre_s, lnpre_b, x);

    unsigned short* wq = wbuf;
    unsigned short* wo = wbuf + WQ_SZ;
    unsigned short* wf = wbuf + WQ_SZ + WO_SZ;
    unsigned short* wp = wbuf + WQ_SZ + WO_SZ + WF_SZ;

    for (int l = 0; l < Lv; l++) {
        convertw_kernel<<<WTOT / 4 / 256, 256, 0, stream>>>(
            qkv_w + (size_t)l * WQ_SZ, out_w + (size_t)l * WO_SZ,
            fc_w + (size_t)l * WF_SZ, proj_w + (size_t)l * WP_SZ, wbuf);
        ln_kernel<<<TOK, 256, 0, stream>>>(x, abuf, ln1_s + l * Dv, ln1_b + l * Dv);
        gemm_mfma<1, 0><<<dim3(2304 / 128, GY, 1), 256, 0, stream>>>(
            abuf, wq, qkv_b + (size_t)l * 2304, nullptr, qkvb, TOK, 2304, Dv);
        attn4_kernel<<<dim3(7, Hh, Bv), 256, 0, stream>>>(qkvb, abuf);
        // out_proj: split-K=2, atomicAdd into x (x holds residual)
        gemm_mfma<2, 0><<<dim3(Dv / 128, GY, 2), 256, 0, stream>>>(
            abuf, wo, out_b + (size_t)l * Dv, nullptr, x, TOK, Dv, Dv);
        ln_kernel<<<TOK, 256, 0, stream>>>(x, abuf, ln2_s + l * Dv, ln2_b + l * Dv);
        gemm_mfma<1, 1><<<dim3(Fv / 128, GY, 1), 256, 0, stream>>>(
            abuf, wf, fc_b + (size_t)l * Fv, nullptr, hbuf, TOK, Fv, Dv);
        // mlp proj: split-K=2, atomicAdd into x (x holds residual)
        gemm_mfma<2, 0><<<dim3(Dv / 128, GY, 2), 256, 0, stream>>>(
            hbuf, wp, proj_b + (size_t)l * Dv, nullptr, x, TOK, Dv, Fv);
    }

    head_kernel<<<Bv, 256, 0, stream>>>(x, lnpost_s, lnpost_b, vis_proj, out);
}

// Round 7
// 4929.374 us; speedup vs baseline: 1.3214x; 1.3214x over previous
//
#include <hip/hip_runtime.h>
#include <cstddef>

#define Bv   32
#define Sv   197
#define Dv   768
#define Hh   12
#define HDv  64
#define Fv   3072
#define Lv   12
#define Ov   512
#define TOK  (Bv * Sv)        // 6304
#define MPAD 6400             // TOK padded (multiple of 256: 25*256)
#define NPATCH 196
#define CONV_M (Bv * NPATCH)  // 6272

#define WQ_SZ (2304 * 768)
#define WO_SZ (768 * 768)
#define WF_SZ (3072 * 768)
#define WP_SZ (768 * 3072)
#define WTOT  (WQ_SZ + WO_SZ + WF_SZ + WP_SZ)   // 7077888

typedef __attribute__((ext_vector_type(8))) __bf16 bf16x8;
typedef __attribute__((ext_vector_type(4))) float f32x4;

__device__ __forceinline__ unsigned short f2bf(float f) {
    unsigned int u = __float_as_uint(f);
    unsigned int r = (u + 0x7fffu + ((u >> 16) & 1u)) >> 16;
    return (unsigned short)r;
}

__device__ __forceinline__ void async_ld16(const void* g, void* l) {
    __builtin_amdgcn_global_load_lds(
        (__attribute__((address_space(1))) void*)(g),
        (__attribute__((address_space(3))) void*)(l),
        16, 0, 0);
}

// ---------------------------------------------------------------------------
// block-wide (256 thread) reduction of two scalars
// ---------------------------------------------------------------------------
__device__ __forceinline__ void reduce2_256(float& s1, float& s2) {
    #pragma unroll
    for (int off = 32; off > 0; off >>= 1) {
        s1 += __shfl_down(s1, off, 64);
        s2 += __shfl_down(s2, off, 64);
    }
    __shared__ float r1[4], r2[4];
    int lane = threadIdx.x & 63, w = threadIdx.x >> 6;
    if (lane == 0) { r1[w] = s1; r2[w] = s2; }
    __syncthreads();
    s1 = r1[0] + r1[1] + r1[2] + r1[3];
    s2 = r2[0] + r2[1] + r2[2] + r2[3];
    __syncthreads();
}

// ---------------------------------------------------------------------------
// weight fp32 -> bf16 conversion
// ---------------------------------------------------------------------------
__global__ void convert_kernel(const float* __restrict__ src,
                               unsigned short* __restrict__ dst, int n4) {
    int gid = blockIdx.x * 256 + threadIdx.x;
    if (gid >= n4) return;
    int idx = gid * 4;
    float4 v = *(const float4*)(src + idx);
    ushort4 r = make_ushort4(f2bf(v.x), f2bf(v.y), f2bf(v.z), f2bf(v.w));
    *(ushort4*)(dst + idx) = r;
}

__global__ void convertw_kernel(const float* __restrict__ wq,
                                const float* __restrict__ wo,
                                const float* __restrict__ wf,
                                const float* __restrict__ wp,
                                unsigned short* __restrict__ dst) {
    int idx = (blockIdx.x * 256 + threadIdx.x) * 4;
    const float* s; int off;
    if (idx < WQ_SZ)                     { s = wq; off = idx; }
    else if (idx < WQ_SZ + WO_SZ)        { s = wo; off = idx - WQ_SZ; }
    else if (idx < WQ_SZ + WO_SZ + WF_SZ){ s = wf; off = idx - WQ_SZ - WO_SZ; }
    else                                 { s = wp; off = idx - WQ_SZ - WO_SZ - WF_SZ; }
    float4 v = *(const float4*)(s + off);
    ushort4 r = make_ushort4(f2bf(v.x), f2bf(v.y), f2bf(v.z), f2bf(v.w));
    *(ushort4*)(dst + idx) = r;
}

// ---------------------------------------------------------------------------
// im2col + normalize -> bf16 patches [6272, 768]
// ---------------------------------------------------------------------------
__global__ void im2col_kernel(const float* __restrict__ img,
                              unsigned short* __restrict__ out) {
    int idx = blockIdx.x * 256 + threadIdx.x;
    int col = idx % 768;
    int row = idx / 768;
    int b = row / NPATCH, p = row % NPATCH;
    int ph = p / 14, pw = p % 14;
    int c  = col >> 8;
    int r  = col & 255;
    int kh = r >> 4, kw = r & 15;
    int y = ph * 16 + kh, x = pw * 16 + kw;
    const float mean[3] = {0.48145466f, 0.4578275f, 0.40821073f};
    const float stdv[3] = {0.26862954f, 0.26130258f, 0.27577711f};
    float v = img[((size_t)(b * 3 + c) * 224 + y) * 224 + x];
    out[idx] = f2bf((v - mean[c]) / stdv[c]);
}

// ---------------------------------------------------------------------------
// MFMA bf16 GEMM: C[m,n] = sum_k A[m,k]*W[n,k] (+bias) (+res fp32) (QuickGELU)
// v8: 256x256 tile, BK=64, 512 threads (8 waves = 2M x 4N, each 128x64).
//  RATIONALE (r0-r6 post-mortems): GEMM time ~= staged_bytes / ~6 TB/s
//  (per-CU ingest pinned ~10 B/cyc across ALL schedules). 256^2 tile halves
//  staged bytes vs 128^2: A staged N/256 times, W staged M/256 times.
//  - staging/read XOR swizzle identical to r3 (verified SQ_LDS_BANK_CONFLICT=0)
//  - global_load_lds DMA staging (r6's reg-staging regressed; reverted)
//  - simple 2-phase dbuf + __syncthreads (schedule proven irrelevant here)
//  - split-K via gridDim.z: ODT==2 -> fp32 atomicAdd into C (C pre-holds
//    residual; bias added by z==0 block only). Split-K doesn't change bytes,
//    only raises block count for N=768 ops (grid 75 -> 300).
//  - XCD-aware bijective remap kept.
// ---------------------------------------------------------------------------
template<int ODT, int ACT>
__global__ __launch_bounds__(512) void gemm_mfma(
        const unsigned short* __restrict__ A, const unsigned short* __restrict__ W,
        const float* __restrict__ bias, const float* __restrict__ res,
        void* __restrict__ Cv, int M, int N, int K)
{
    __shared__ unsigned short As[2][256 * 64];   // 2 x 32 KB
    __shared__ unsigned short Ws[2][256 * 64];   // 2 x 32 KB
    const int tid = threadIdx.x;
    const int w = tid >> 6, l = tid & 63;

    // ---- XCD-aware bijective remap of linear workgroup id (T1, m204) ----
    const int gx = gridDim.x;
    const int wg  = blockIdx.y * gx + blockIdx.x;
    const int nwg = gx * gridDim.y;
    const int q = nwg >> 3, r8 = nwg & 7;
    const int xcd = wg & 7, lo = wg >> 3;
    const int swz = (xcd < r8 ? xcd * (q + 1) : r8 * (q + 1) + (xcd - r8) * q) + lo;
    const int m0 = (swz / gx) << 8;      // 256-row tile
    const int n0 = (swz % gx) << 8;      // 256-col tile

    // ---- split-K ----
    const int kseg  = K / gridDim.z;
    const int kbase = blockIdx.z * kseg;

    // ---- staging (r3-verified): pre-swizzled global src, linear LDS dest ----
    // per instr: 64 lanes x 16B = 1 KB = 8 rows x 64 cols(bf16).
    // lane l -> row l>>3, src 16B-chunk (l&7)^(l>>3); wave w instr i covers
    // rows [w*8 + i*64, +8) of the 256-row tile (i = 0..3, for A and W).
    const int lrow = l >> 3;
    const int lchk = (l & 7) ^ lrow;
    const unsigned short* agp = A + (size_t)(m0 + w * 8 + lrow) * K + kbase + lchk * 8;
    const unsigned short* wgp = W + (size_t)(n0 + w * 8 + lrow) * K + kbase + lchk * 8;
    const int lbase = (w * 8) * 64;      // shorts; + i*64*64 per instr

    // ---- fragment read offsets (swizzled; r3-verified pattern) ----
    const int wm = w >> 2, wn = w & 3;   // 2M x 4N waves; wave = 128x64 out
    const int fr = l & 15, fq = l >> 4;
    int aoff[2][8], woff[2][4];
    #pragma unroll
    for (int ks = 0; ks < 2; ks++) {
        const int pc = ((ks * 4 + fq) ^ (fr & 7)) * 8;
        #pragma unroll
        for (int i = 0; i < 8; i++)
            aoff[ks][i] = (wm * 128 + i * 16 + fr) * 64 + pc;
        #pragma unroll
        for (int j = 0; j < 4; j++)
            woff[ks][j] = (wn * 64 + j * 16 + fr) * 64 + pc;
    }

    f32x4 acc[8][4] = {};
    const int nt = kseg >> 6;   // BK=64

    #define STAGE(t, bf) do {                                              \
        const int _ko = (t) << 6;                                          \
        _Pragma("unroll")                                                  \
        for (int _i = 0; _i < 4; _i++)                                     \
            async_ld16(agp + (size_t)_i * 64 * K + _ko,                    \
                       &As[bf][lbase + _i * 64 * 64]);                     \
        _Pragma("unroll")                                                  \
        for (int _i = 0; _i < 4; _i++)                                     \
            async_ld16(wgp + (size_t)_i * 64 * K + _ko,                    \
                       &Ws[bf][lbase + _i * 64 * 64]);                     \
    } while (0)

    auto compute = [&](const unsigned short* ab, const unsigned short* wb) {
        #pragma unroll
        for (int ks = 0; ks < 2; ks++) {
            bf16x8 wf[4];
            #pragma unroll
            for (int j = 0; j < 4; j++)
                wf[j] = *(const bf16x8*)(wb + woff[ks][j]);
            #pragma unroll
            for (int i = 0; i < 8; i++) {
                bf16x8 af = *(const bf16x8*)(ab + aoff[ks][i]);
                #pragma unroll
                for (int j = 0; j < 4; j++) {
                    acc[i][j] = __builtin_amdgcn_mfma_f32_16x16x32_bf16(
                        af, wf[j], acc[i][j], 0, 0, 0);
                }
            }
        }
    };

    // prologue
    STAGE(0, 0);
    __syncthreads();

    int bf = 0;
    for (int t = 0; t < nt; t++) {
        if (t + 1 < nt) STAGE(t + 1, bf ^ 1);
        compute(As[bf], Ws[bf]);
        __syncthreads();        // staged t+1 landed; all reads of bf consumed
        bf ^= 1;
    }
    #undef STAGE

    const bool addb = (ODT != 2) || (blockIdx.z == 0);
    float bn[4];
    #pragma unroll
    for (int j = 0; j < 4; j++)
        bn[j] = (bias && addb) ? bias[n0 + wn * 64 + j * 16 + fr] : 0.f;

    #pragma unroll
    for (int i = 0; i < 8; i++) {
        #pragma unroll
        for (int r = 0; r < 4; r++) {
            int m = m0 + wm * 128 + i * 16 + fq * 4 + r;
            if (m < M) {
                size_t rowb = (size_t)m * N;
                #pragma unroll
                for (int j = 0; j < 4; j++) {
                    int n = n0 + wn * 64 + j * 16 + fr;
                    float v = acc[i][j][r] + bn[j];
                    if (ODT == 2) {
                        atomicAdd((float*)Cv + rowb + n, v);
                    } else {
                        if (res) v += res[rowb + n];
                        if (ACT) v = v / (1.f + __expf(-1.702f * v));
                        if (ODT == 0) ((float*)Cv)[rowb + n] = v;
                        else ((unsigned short*)Cv)[rowb + n] = f2bf(v);
                    }
                }
            }
        }
    }
}

// ---------------------------------------------------------------------------
// LayerNorm fp32 in -> bf16 out. One block per token.
// ---------------------------------------------------------------------------
__global__ void ln_kernel(const float* __restrict__ in, unsigned short* __restrict__ out,
                          const float* __restrict__ s, const float* __restrict__ b) {
    int t = blockIdx.x;
    const float* row = in + (size_t)t * Dv;
    int tid = threadIdx.x;
    float v[3], s1 = 0.f, s2 = 0.f;
    #pragma unroll
    for (int i = 0; i < 3; i++) {
        v[i] = row[tid + 256 * i];
        s1 += v[i]; s2 += v[i] * v[i];
    }
    reduce2_256(s1, s2);
    float mean = s1 * (1.0f / Dv);
    float var  = s2 * (1.0f / Dv) - mean * mean;
    float rstd = rsqrtf(var + 1e-5f);
    unsigned short* orow = out + (size_t)t * Dv;
    #pragma unroll
    for (int i = 0; i < 3; i++) {
        int d = tid + 256 * i;
        orow[d] = f2bf((v[i] - mean) * rstd * s[d] + b[d]);
    }
}

// ---------------------------------------------------------------------------
// embed (cls/patch + pos) + ln_pre -> x fp32. One block per token.
// ---------------------------------------------------------------------------
__global__ void embed_ln_kernel(const float* __restrict__ conv_out,
                                const float* __restrict__ cls,
                                const float* __restrict__ pos,
                                const float* __restrict__ s,
                                const float* __restrict__ b,
                                float* __restrict__ x) {
    int t = blockIdx.x;
    int bb = t / Sv, si = t % Sv;
    int tid = threadIdx.x;
    float v[3], s1 = 0.f, s2 = 0.f;
    #pragma unroll
    for (int i = 0; i < 3; i++) {
        int d = tid + 256 * i;
        float e = (si == 0) ? cls[d]
                            : conv_out[((size_t)bb * NPATCH + (si - 1)) * Dv + d];
        v[i] = e + pos[(size_t)si * Dv + d];
        s1 += v[i]; s2 += v[i] * v[i];
    }
    reduce2_256(s1, s2);
    float mean = s1 * (1.0f / Dv);
    float var  = s2 * (1.0f / Dv) - mean * mean;
    float rstd = rsqrtf(var + 1e-5f);
    float* orow = x + (size_t)t * Dv;
    #pragma unroll
    for (int i = 0; i < 3; i++) {
        int d = tid + 256 * i;
        orow[d] = (v[i] - mean) * rstd * s[d] + b[d];
    }
}

// ---------------------------------------------------------------------------
// Attention v4 (MFMA): grid (7, H, B); block = 256 thr = 4 waves; 32 q-rows.
// ---------------------------------------------------------------------------
__global__ __launch_bounds__(256) void attn4_kernel(
        const unsigned short* __restrict__ qkv, unsigned short* __restrict__ o) {
    const int qg = blockIdx.x, h = blockIdx.y, b = blockIdx.z;
    __shared__ __align__(16) unsigned short vt[64][232];   // V^T [d][j], 29.7 KB
    __shared__ __align__(16) unsigned short pb[32][236];   // P bf16 [row][k], 14.8 KB
    __shared__ float red[4][32];
    __shared__ float smax_f[32];
    __shared__ float sinv_f[32];

    const int tid = threadIdx.x;
    const int w = tid >> 6, l = tid & 63;
    const int fr = l & 15, fq = l >> 4;
    const size_t base = (size_t)b * Sv;
    const unsigned int* q32 = (const unsigned int*)qkv;    // row stride 1152 uints

    // ---- stage V^T (cols >= 197 zeroed) ----
    for (int i = tid; i < 224 * 32; i += 256) {
        int j = i >> 5, u = i & 31;
        unsigned int val = (j < Sv) ? q32[(base + j) * 1152 + 768 + h * 32 + u] : 0u;
        vt[2 * u][j]     = (unsigned short)(val & 0xffffu);
        vt[2 * u + 1][j] = (unsigned short)(val >> 16);
    }

    union U { uint4 u; bf16x8 v; };

    // ---- QK^T: sc[mt][s], rows qg*32+mt*16+fq*4+r, cols (w+4s)*16+fr ----
    f32x4 sc[2][4] = {};
    #pragma unroll
    for (int ks = 0; ks < 2; ks++) {
        U aq[2];
        #pragma unroll
        for (int mt = 0; mt < 2; mt++) {
            int row = qg * 32 + mt * 16 + fr;
            int rc = row < Sv ? row : Sv - 1;
            aq[mt].u = *(const uint4*)(qkv + (base + rc) * 2304 + h * 64 + ks * 32 + fq * 8);
        }
        #pragma unroll
        for (int s = 0; s < 4; s++) {
            int nt = w + 4 * s;
            if (nt >= 14) continue;
            int col = nt * 16 + fr;
            int cc = col < Sv ? col : Sv - 1;
            U bq;
            bq.u = *(const uint4*)(qkv + (base + cc) * 2304 + 768 + h * 64 + ks * 32 + fq * 8);
            #pragma unroll
            for (int mt = 0; mt < 2; mt++)
                sc[mt][s] = __builtin_amdgcn_mfma_f32_16x16x32_bf16(
                    aq[mt].v, bq.v, sc[mt][s], 0, 0, 0);
        }
    }

    // ---- scale + mask + row max ----
    float rmax[2][4];
    #pragma unroll
    for (int mt = 0; mt < 2; mt++)
        #pragma unroll
        for (int r = 0; r < 4; r++) rmax[mt][r] = -1e30f;
    #pragma unroll
    for (int mt = 0; mt < 2; mt++) {
        #pragma unroll
        for (int s = 0; s < 4; s++) {
            int nt = w + 4 * s;
            int col = nt * 16 + fr;
            bool valid = (nt < 14) && (col < Sv);
            #pragma unroll
            for (int r = 0; r < 4; r++) {
                float v = valid ? sc[mt][s][r] * 0.125f : -1e30f;
                sc[mt][s][r] = v;
                rmax[mt][r] = fmaxf(rmax[mt][r], v);
            }
        }
    }
    #pragma unroll
    for (int mt = 0; mt < 2; mt++) {
        #pragma unroll
        for (int r = 0; r < 4; r++) {
            float m = rmax[mt][r];
            m = fmaxf(m, __shfl_xor(m, 1, 64));
            m = fmaxf(m, __shfl_xor(m, 2, 64));
            m = fmaxf(m, __shfl_xor(m, 4, 64));
            m = fmaxf(m, __shfl_xor(m, 8, 64));
            rmax[mt][r] = m;
        }
    }
    if (fr == 0) {
        #pragma unroll
        for (int mt = 0; mt < 2; mt++)
            #pragma unroll
            for (int r = 0; r < 4; r++)
                red[w][mt * 16 + fq * 4 + r] = rmax[mt][r];
    }
    __syncthreads();
    if (tid < 32)
        smax_f[tid] = fmaxf(fmaxf(red[0][tid], red[1][tid]),
                            fmaxf(red[2][tid], red[3][tid]));
    __syncthreads();

    // ---- exp + row sum + write P (bf16, A layout) ----
    float rsum[2][4] = {};
    #pragma unroll
    for (int mt = 0; mt < 2; mt++) {
        float fm[4];
        #pragma unroll
        for (int r = 0; r < 4; r++) fm[r] = smax_f[mt * 16 + fq * 4 + r];
        #pragma unroll
        for (int s = 0; s < 4; s++) {
            int nt = w + 4 * s;
            if (nt >= 14) continue;
            int col = nt * 16 + fr;
            #pragma unroll
            for (int r = 0; r < 4; r++) {
                float p = (col < Sv) ? __expf(sc[mt][s][r] - fm[r]) : 0.f;
                rsum[mt][r] += p;
                pb[mt * 16 + fq * 4 + r][col] = f2bf(p);
            }
        }
    }
    #pragma unroll
    for (int mt = 0; mt < 2; mt++) {
        #pragma unroll
        for (int r = 0; r < 4; r++) {
            float s = rsum[mt][r];
            s += __shfl_xor(s, 1, 64);
            s += __shfl_xor(s, 2, 64);
            s += __shfl_xor(s, 4, 64);
            s += __shfl_xor(s, 8, 64);
            rsum[mt][r] = s;
        }
    }
    if (fr == 0) {
        #pragma unroll
        for (int mt = 0; mt < 2; mt++)
            #pragma unroll
            for (int r = 0; r < 4; r++)
                red[w][mt * 16 + fq * 4 + r] = rsum[mt][r];
    }
    __syncthreads();
    if (tid < 32)
        sinv_f[tid] = 1.f / (red[0][tid] + red[1][tid] + red[2][tid] + red[3][tid]);
    __syncthreads();   // also guarantees vt + pb staging complete

    // ---- PV: wave w -> output dims [w*16, w*16+16) ----
    f32x4 oc[2] = {};
    #pragma unroll
    for (int ks = 0; ks < 7; ks++) {
        U bv;
        bv.u = *(const uint4*)&vt[w * 16 + fr][ks * 32 + fq * 8];
        #pragma unroll
        for (int mt = 0; mt < 2; mt++) {
            const unsigned short* ap = &pb[mt * 16 + fr][ks * 32 + fq * 8];
            uint2 lo = *(const uint2*)ap;
            uint2 hi = *(const uint2*)(ap + 4);
            U a; a.u = make_uint4(lo.x, lo.y, hi.x, hi.y);
            oc[mt] = __builtin_amdgcn_mfma_f32_16x16x32_bf16(a.v, bv.v, oc[mt], 0, 0, 0);
        }
    }

    // ---- epilogue: /= rowsum, store bf16 ----
    #pragma unroll
    for (int mt = 0; mt < 2; mt++) {
        #pragma unroll
        for (int r = 0; r < 4; r++) {
            int lrow = mt * 16 + fq * 4 + r;
            int row = qg * 32 + lrow;
            if (row < Sv)
                o[(base + row) * Dv + h * 64 + w * 16 + fr] =
                    f2bf(oc[mt][r] * sinv_f[lrow]);
        }
    }
}

// ---------------------------------------------------------------------------
// Head: ln_post on cls token + @ vis_proj [768,512] fp32. One block per batch.
// ---------------------------------------------------------------------------
__global__ void head_kernel(const float* __restrict__ x,
                            const float* __restrict__ s, const float* __restrict__ b,
                            const float* __restrict__ vp, float* __restrict__ out) {
    int bb = blockIdx.x, tid = threadIdx.x;
    __shared__ float xn[Dv];
    const float* row = x + (size_t)(bb * Sv) * Dv;
    float v[3], s1 = 0.f, s2 = 0.f;
    #pragma unroll
    for (int i = 0; i < 3; i++) {
        v[i] = row[tid + 256 * i];
        s1 += v[i]; s2 += v[i] * v[i];
    }
    reduce2_256(s1, s2);
    float mean = s1 * (1.0f / Dv);
    float var  = s2 * (1.0f / Dv) - mean * mean;
    float rstd = rsqrtf(var + 1e-5f);
    #pragma unroll
    for (int i = 0; i < 3; i++) {
        int d = tid + 256 * i;
        xn[d] = (v[i] - mean) * rstd * s[d] + b[d];
    }
    __syncthreads();
    float acc0 = 0.f, acc1 = 0.f;
    for (int d = 0; d < Dv; d++) {
        float xv = xn[d];
        acc0 += xv * vp[(size_t)d * Ov + tid];
        acc1 += xv * vp[(size_t)d * Ov + tid + 256];
    }
    out[(size_t)bb * Ov + tid]       = acc0;
    out[(size_t)bb * Ov + tid + 256] = acc1;
}

// ---------------------------------------------------------------------------
extern "C" void kernel_launch(void* const* d_in, const int* in_sizes, int n_in,
                              void* d_out, int out_size, void* d_ws, size_t ws_size,
                              hipStream_t stream) {
    const float* images   = (const float*)d_in[0];
    const float* conv_w   = (const float*)d_in[1];
    const float* cls_emb  = (const float*)d_in[2];
    const float* pos_emb  = (const float*)d_in[3];
    const float* lnpre_s  = (const float*)d_in[4];
    const float* lnpre_b  = (const float*)d_in[5];
    const float* ln1_s    = (const float*)d_in[6];
    const float* ln1_b    = (const float*)d_in[7];
    const float* qkv_w    = (const float*)d_in[8];
    const float* qkv_b    = (const float*)d_in[9];
    const float* out_w    = (const float*)d_in[10];
    const float* out_b    = (const float*)d_in[11];
    const float* ln2_s    = (const float*)d_in[12];
    const float* ln2_b    = (const float*)d_in[13];
    const float* fc_w     = (const float*)d_in[14];
    const float* fc_b     = (const float*)d_in[15];
    const float* proj_w   = (const float*)d_in[16];
    const float* proj_b   = (const float*)d_in[17];
    const float* lnpost_s = (const float*)d_in[18];
    const float* lnpost_b = (const float*)d_in[19];
    const float* vis_proj = (const float*)d_in[20];
    float* out = (float*)d_out;

    char* p = (char*)d_ws;
    float* x              = (float*)p;          p += (size_t)TOK * Dv * 4;       // 19.4 MB
    unsigned short* abuf  = (unsigned short*)p; p += (size_t)MPAD * Dv * 2;      //  9.8 MB
    unsigned short* qkvb  = (unsigned short*)p; p += (size_t)MPAD * 2304 * 2;    // 29.5 MB
    unsigned short* hbuf  = (unsigned short*)p; p += (size_t)MPAD * Fv * 2;      // 39.3 MB
    unsigned short* wbuf  = (unsigned short*)p; p += (size_t)WTOT * 2;           // 14.2 MB
    unsigned short* cwb   = (unsigned short*)p; p += (size_t)WO_SZ * 2;          //  1.2 MB
    // aliases (pre-loop only):
    unsigned short* im2c  = qkvb;               // [6272,768] bf16 (rows to 6400 readable)
    float* convo          = (float*)hbuf;       // [6272,768] fp32

    const int GY = MPAD / 256;   // 25 row-tiles (covers conv's 6272 too)

    // patch embedding
    convert_kernel<<<WO_SZ / 4 / 256, 256, 0, stream>>>(conv_w, cwb, WO_SZ / 4);
    im2col_kernel<<<(CONV_M * Dv) / 256, 256, 0, stream>>>(images, im2c);
    gemm_mfma<0, 0><<<dim3(Dv / 256, GY, 1), 512, 0, stream>>>(
        im2c, cwb, nullptr, nullptr, convo, CONV_M, Dv, Dv);
    embed_ln_kernel<<<TOK, 256, 0, stream>>>(convo, cls_emb, pos_emb,
                                             lnpre_s, lnpre_b, x);

    unsigned short* wq = wbuf;
    unsigned short* wo = wbuf + WQ_SZ;
    unsigned short* wf = wbuf + WQ_SZ + WO_SZ;
    unsigned short* wp = wbuf + WQ_SZ + WO_SZ + WF_SZ;

    for (int l = 0; l < Lv; l++) {
        convertw_kernel<<<WTOT / 4 / 256, 256, 0, stream>>>(
            qkv_w + (size_t)l * WQ_SZ, out_w + (size_t)l * WO_SZ,
            fc_w + (size_t)l * WF_SZ, proj_w + (size_t)l * WP_SZ, wbuf);
        ln_kernel<<<TOK, 256, 0, stream>>>(x, abuf, ln1_s + l * Dv, ln1_b + l * Dv);
        gemm_mfma<1, 0><<<dim3(2304 / 256, GY, 1), 512, 0, stream>>>(
            abuf, wq, qkv_b + (size_t)l * 2304, nullptr, qkvb, TOK, 2304, Dv);
        attn4_kernel<<<dim3(7, Hh, Bv), 256, 0, stream>>>(qkvb, abuf);
        // out_proj: split-K=4 (300 blocks), atomicAdd into x (x holds residual)
        gemm_mfma<2, 0><<<dim3(Dv / 256, GY, 4), 512, 0, stream>>>(
            abuf, wo, out_b + (size_t)l * Dv, nullptr, x, TOK, Dv, Dv);
        ln_kernel<<<TOK, 256, 0, stream>>>(x, abuf, ln2_s + l * Dv, ln2_b + l * Dv);
        gemm_mfma<1, 1><<<dim3(Fv / 256, GY, 1), 512, 0, stream>>>(
            abuf, wf, fc_b + (size_t)l * Fv, nullptr, hbuf, TOK, Fv, Dv);
        // mlp proj: split-K=4 (300 blocks), atomicAdd into x (x holds residual)
        gemm_mfma<2, 0><<<dim3(Dv / 256, GY, 4), 512, 0, stream>>>(
            hbuf, wp, proj_b + (size_t)l * Dv, nullptr, x, TOK, Dv, Fv);
    }

    head_kernel<<<Bv, 256, 0, stream>>>(x, lnpost_s, lnpost_b, vis_proj, out);
}

// Round 8
// 4386.566 us; speedup vs baseline: 1.4850x; 1.1237x over previous
//
#include <hip/hip_runtime.h>
#include <cstddef>

#define Bv   32
#define Sv   197
#define Dv   768
#define Hh   12
#define HDv  64
#define Fv   3072
#define Lv   12
#define Ov   512
#define TOK  (Bv * Sv)        // 6304
#define MPAD 6400             // TOK padded (multiple of 256: 25*256)
#define NPATCH 196
#define CONV_M (Bv * NPATCH)  // 6272

#define WQ_SZ (2304 * 768)
#define WO_SZ (768 * 768)
#define WF_SZ (3072 * 768)
#define WP_SZ (768 * 3072)
#define WTOT  (WQ_SZ + WO_SZ + WF_SZ + WP_SZ)   // 7077888

typedef __attribute__((ext_vector_type(8))) __bf16 bf16x8;
typedef __attribute__((ext_vector_type(4))) float f32x4;

__device__ __forceinline__ unsigned short f2bf(float f) {
    unsigned int u = __float_as_uint(f);
    unsigned int r = (u + 0x7fffu + ((u >> 16) & 1u)) >> 16;
    return (unsigned short)r;
}

__device__ __forceinline__ void async_ld16(const void* g, void* l) {
    __builtin_amdgcn_global_load_lds(
        (__attribute__((address_space(1))) void*)(g),
        (__attribute__((address_space(3))) void*)(l),
        16, 0, 0);
}

// ---------------------------------------------------------------------------
// block-wide (256 thread) reduction of two scalars
// ---------------------------------------------------------------------------
__device__ __forceinline__ void reduce2_256(float& s1, float& s2) {
    #pragma unroll
    for (int off = 32; off > 0; off >>= 1) {
        s1 += __shfl_down(s1, off, 64);
        s2 += __shfl_down(s2, off, 64);
    }
    __shared__ float r1[4], r2[4];
    int lane = threadIdx.x & 63, w = threadIdx.x >> 6;
    if (lane == 0) { r1[w] = s1; r2[w] = s2; }
    __syncthreads();
    s1 = r1[0] + r1[1] + r1[2] + r1[3];
    s2 = r2[0] + r2[1] + r2[2] + r2[3];
    __syncthreads();
}

// ---------------------------------------------------------------------------
// weight fp32 -> bf16 conversion
// ---------------------------------------------------------------------------
__global__ void convert_kernel(const float* __restrict__ src,
                               unsigned short* __restrict__ dst, int n4) {
    int gid = blockIdx.x * 256 + threadIdx.x;
    if (gid >= n4) return;
    int idx = gid * 4;
    float4 v = *(const float4*)(src + idx);
    ushort4 r = make_ushort4(f2bf(v.x), f2bf(v.y), f2bf(v.z), f2bf(v.w));
    *(ushort4*)(dst + idx) = r;
}

__global__ void convertw_kernel(const float* __restrict__ wq,
                                const float* __restrict__ wo,
                                const float* __restrict__ wf,
                                const float* __restrict__ wp,
                                unsigned short* __restrict__ dst) {
    int idx = (blockIdx.x * 256 + threadIdx.x) * 4;
    const float* s; int off;
    if (idx < WQ_SZ)                     { s = wq; off = idx; }
    else if (idx < WQ_SZ + WO_SZ)        { s = wo; off = idx - WQ_SZ; }
    else if (idx < WQ_SZ + WO_SZ + WF_SZ){ s = wf; off = idx - WQ_SZ - WO_SZ; }
    else                                 { s = wp; off = idx - WQ_SZ - WO_SZ - WF_SZ; }
    float4 v = *(const float4*)(s + off);
    ushort4 r = make_ushort4(f2bf(v.x), f2bf(v.y), f2bf(v.z), f2bf(v.w));
    *(ushort4*)(dst + idx) = r;
}

// ---------------------------------------------------------------------------
// im2col + normalize -> bf16 patches [6272, 768]
// ---------------------------------------------------------------------------
__global__ void im2col_kernel(const float* __restrict__ img,
                              unsigned short* __restrict__ out) {
    int idx = blockIdx.x * 256 + threadIdx.x;
    int col = idx % 768;
    int row = idx / 768;
    int b = row / NPATCH, p = row % NPATCH;
    int ph = p / 14, pw = p % 14;
    int c  = col >> 8;
    int r  = col & 255;
    int kh = r >> 4, kw = r & 15;
    int y = ph * 16 + kh, x = pw * 16 + kw;
    const float mean[3] = {0.48145466f, 0.4578275f, 0.40821073f};
    const float stdv[3] = {0.26862954f, 0.26130258f, 0.27577711f};
    float v = img[((size_t)(b * 3 + c) * 224 + y) * 224 + x];
    out[idx] = f2bf((v - mean[c]) / stdv[c]);
}

// ---------------------------------------------------------------------------
// MFMA bf16 GEMM: C[m,n] = sum_k A[m,k]*W[n,k] (+bias) (+res fp32) (QuickGELU)
// v9: BM=256, BN template (256 or 128), BK=64, 512 threads (8 waves).
//  Post-mortem law (r0-r7): time ~= staged_bytes/(active_CUs x 24 GB/s)
//                              + atomic_write_bytes x ~1 us/MB.
//  - BN=256 (waves 2Mx4N, each 128x64): qkv/fc/conv -- halves staged bytes
//    (validated r7: these left the top-5).
//  - BN=128 (waves 4Mx2N, each 64x64, r3-verified geometry) + split-K=2:
//    out/proj -- 300 blocks (all CUs), atomic writes halved vs r7's z=4.
//  - staging/read XOR swizzle verbatim from r3/r7 (SQ_LDS_BANK_CONFLICT=0).
//  - split-K via gridDim.z: ODT==2 -> fp32 atomicAdd into C (C pre-holds
//    residual; bias added by z==0 block only).
//  - XCD-aware bijective remap kept.
// ---------------------------------------------------------------------------
template<int ODT, int ACT, int BN>
__global__ __launch_bounds__(512) void gemm_mfma(
        const unsigned short* __restrict__ A, const unsigned short* __restrict__ W,
        const float* __restrict__ bias, const float* __restrict__ res,
        void* __restrict__ Cv, int M, int N, int K)
{
    constexpr int WN = (BN == 256) ? 4 : 2;   // waves along N
    constexpr int WM = 8 / WN;                // waves along M
    constexpr int MI = 256 / WM / 16;         // A-fragments per wave (8 or 4)
    constexpr int NI = BN / WN / 16;          // W-fragments per wave (4)
    constexpr int NWI = BN / 64;              // W stage instrs (4 or 2)

    __shared__ unsigned short As[2][256 * 64];
    __shared__ unsigned short Ws[2][BN * 64];
    const int tid = threadIdx.x;
    const int w = tid >> 6, l = tid & 63;

    // ---- XCD-aware bijective remap of linear workgroup id (T1, m204) ----
    const int gx = gridDim.x;
    const int wg  = blockIdx.y * gx + blockIdx.x;
    const int nwg = gx * gridDim.y;
    const int q = nwg >> 3, r8 = nwg & 7;
    const int xcd = wg & 7, lo = wg >> 3;
    const int swz = (xcd < r8 ? xcd * (q + 1) : r8 * (q + 1) + (xcd - r8) * q) + lo;
    const int m0 = (swz / gx) << 8;      // 256-row tile
    const int n0 = (swz % gx) * BN;      // BN-col tile

    // ---- split-K ----
    const int kseg  = K / gridDim.z;
    const int kbase = blockIdx.z * kseg;

    // ---- staging (r3-verified): pre-swizzled global src, linear LDS dest ----
    // per instr: 64 lanes x 16B = 1 KB = 8 rows x 64 cols(bf16).
    // lane l -> row l>>3, src 16B-chunk (l&7)^(l>>3); wave w instr i covers
    // rows [w*8 + i*64, +8).
    const int lrow = l >> 3;
    const int lchk = (l & 7) ^ lrow;
    const unsigned short* agp = A + (size_t)(m0 + w * 8 + lrow) * K + kbase + lchk * 8;
    const unsigned short* wgp = W + (size_t)(n0 + w * 8 + lrow) * K + kbase + lchk * 8;
    const int lbase = (w * 8) * 64;      // shorts; + i*64*64 per instr

    // ---- fragment read offsets (swizzled; r3-verified pattern) ----
    const int wm = w / WN, wn = w % WN;
    const int fr = l & 15, fq = l >> 4;
    int aoff[2][MI], woff[2][NI];
    #pragma unroll
    for (int ks = 0; ks < 2; ks++) {
        const int pc = ((ks * 4 + fq) ^ (fr & 7)) * 8;
        #pragma unroll
        for (int i = 0; i < MI; i++)
            aoff[ks][i] = (wm * (MI * 16) + i * 16 + fr) * 64 + pc;
        #pragma unroll
        for (int j = 0; j < NI; j++)
            woff[ks][j] = (wn * (NI * 16) + j * 16 + fr) * 64 + pc;
    }

    f32x4 acc[MI][NI] = {};
    const int nt = kseg >> 6;   // BK=64

    #define STAGE(t, bf) do {                                              \
        const int _ko = (t) << 6;                                          \
        _Pragma("unroll")                                                  \
        for (int _i = 0; _i < 4; _i++)                                     \
            async_ld16(agp + (size_t)_i * 64 * K + _ko,                    \
                       &As[bf][lbase + _i * 64 * 64]);                     \
        _Pragma("unroll")                                                  \
        for (int _i = 0; _i < NWI; _i++)                                   \
            async_ld16(wgp + (size_t)_i * 64 * K + _ko,                    \
                       &Ws[bf][lbase + _i * 64 * 64]);                     \
    } while (0)

    auto compute = [&](const unsigned short* ab, const unsigned short* wb) {
        #pragma unroll
        for (int ks = 0; ks < 2; ks++) {
            bf16x8 wf[NI];
            #pragma unroll
            for (int j = 0; j < NI; j++)
                wf[j] = *(const bf16x8*)(wb + woff[ks][j]);
            #pragma unroll
            for (int i = 0; i < MI; i++) {
                bf16x8 af = *(const bf16x8*)(ab + aoff[ks][i]);
                #pragma unroll
                for (int j = 0; j < NI; j++) {
                    acc[i][j] = __builtin_amdgcn_mfma_f32_16x16x32_bf16(
                        af, wf[j], acc[i][j], 0, 0, 0);
                }
            }
        }
    };

    // prologue
    STAGE(0, 0);
    __syncthreads();

    int bf = 0;
    for (int t = 0; t < nt; t++) {
        if (t + 1 < nt) STAGE(t + 1, bf ^ 1);
        compute(As[bf], Ws[bf]);
        __syncthreads();        // staged t+1 landed; all reads of bf consumed
        bf ^= 1;
    }
    #undef STAGE

    const bool addb = (ODT != 2) || (blockIdx.z == 0);
    float bn[NI];
    #pragma unroll
    for (int j = 0; j < NI; j++)
        bn[j] = (bias && addb) ? bias[n0 + wn * (NI * 16) + j * 16 + fr] : 0.f;

    #pragma unroll
    for (int i = 0; i < MI; i++) {
        #pragma unroll
        for (int r = 0; r < 4; r++) {
            int m = m0 + wm * (MI * 16) + i * 16 + fq * 4 + r;
            if (m < M) {
                size_t rowb = (size_t)m * N;
                #pragma unroll
                for (int j = 0; j < NI; j++) {
                    int n = n0 + wn * (NI * 16) + j * 16 + fr;
                    float v = acc[i][j][r] + bn[j];
                    if (ODT == 2) {
                        atomicAdd((float*)Cv + rowb + n, v);
                    } else {
                        if (res) v += res[rowb + n];
                        if (ACT) v = v / (1.f + __expf(-1.702f * v));
                        if (ODT == 0) ((float*)Cv)[rowb + n] = v;
                        else ((unsigned short*)Cv)[rowb + n] = f2bf(v);
                    }
                }
            }
        }
    }
}

// ---------------------------------------------------------------------------
// LayerNorm fp32 in -> bf16 out. One block per token.
// ---------------------------------------------------------------------------
__global__ void ln_kernel(const float* __restrict__ in, unsigned short* __restrict__ out,
                          const float* __restrict__ s, const float* __restrict__ b) {
    int t = blockIdx.x;
    const float* row = in + (size_t)t * Dv;
    int tid = threadIdx.x;
    float v[3], s1 = 0.f, s2 = 0.f;
    #pragma unroll
    for (int i = 0; i < 3; i++) {
        v[i] = row[tid + 256 * i];
        s1 += v[i]; s2 += v[i] * v[i];
    }
    reduce2_256(s1, s2);
    float mean = s1 * (1.0f / Dv);
    float var  = s2 * (1.0f / Dv) - mean * mean;
    float rstd = rsqrtf(var + 1e-5f);
    unsigned short* orow = out + (size_t)t * Dv;
    #pragma unroll
    for (int i = 0; i < 3; i++) {
        int d = tid + 256 * i;
        orow[d] = f2bf((v[i] - mean) * rstd * s[d] + b[d]);
    }
}

// ---------------------------------------------------------------------------
// embed (cls/patch + pos) + ln_pre -> x fp32. One block per token.
// ---------------------------------------------------------------------------
__global__ void embed_ln_kernel(const float* __restrict__ conv_out,
                                const float* __restrict__ cls,
                                const float* __restrict__ pos,
                                const float* __restrict__ s,
                                const float* __restrict__ b,
                                float* __restrict__ x) {
    int t = blockIdx.x;
    int bb = t / Sv, si = t % Sv;
    int tid = threadIdx.x;
    float v[3], s1 = 0.f, s2 = 0.f;
    #pragma unroll
    for (int i = 0; i < 3; i++) {
        int d = tid + 256 * i;
        float e = (si == 0) ? cls[d]
                            : conv_out[((size_t)bb * NPATCH + (si - 1)) * Dv + d];
        v[i] = e + pos[(size_t)si * Dv + d];
        s1 += v[i]; s2 += v[i] * v[i];
    }
    reduce2_256(s1, s2);
    float mean = s1 * (1.0f / Dv);
    float var  = s2 * (1.0f / Dv) - mean * mean;
    float rstd = rsqrtf(var + 1e-5f);
    float* orow = x + (size_t)t * Dv;
    #pragma unroll
    for (int i = 0; i < 3; i++) {
        int d = tid + 256 * i;
        orow[d] = (v[i] - mean) * rstd * s[d] + b[d];
    }
}

// ---------------------------------------------------------------------------
// Attention v4 (MFMA): grid (7, H, B); block = 256 thr = 4 waves; 32 q-rows.
// ---------------------------------------------------------------------------
__global__ __launch_bounds__(256) void attn4_kernel(
        const unsigned short* __restrict__ qkv, unsigned short* __restrict__ o) {
    const int qg = blockIdx.x, h = blockIdx.y, b = blockIdx.z;
    __shared__ __align__(16) unsigned short vt[64][232];   // V^T [d][j], 29.7 KB
    __shared__ __align__(16) unsigned short pb[32][236];   // P bf16 [row][k], 14.8 KB
    __shared__ float red[4][32];
    __shared__ float smax_f[32];
    __shared__ float sinv_f[32];

    const int tid = threadIdx.x;
    const int w = tid >> 6, l = tid & 63;
    const int fr = l & 15, fq = l >> 4;
    const size_t base = (size_t)b * Sv;
    const unsigned int* q32 = (const unsigned int*)qkv;    // row stride 1152 uints

    // ---- stage V^T (cols >= 197 zeroed) ----
    for (int i = tid; i < 224 * 32; i += 256) {
        int j = i >> 5, u = i & 31;
        unsigned int val = (j < Sv) ? q32[(base + j) * 1152 + 768 + h * 32 + u] : 0u;
        vt[2 * u][j]     = (unsigned short)(val & 0xffffu);
        vt[2 * u + 1][j] = (unsigned short)(val >> 16);
    }

    union U { uint4 u; bf16x8 v; };

    // ---- QK^T: sc[mt][s], rows qg*32+mt*16+fq*4+r, cols (w+4s)*16+fr ----
    f32x4 sc[2][4] = {};
    #pragma unroll
    for (int ks = 0; ks < 2; ks++) {
        U aq[2];
        #pragma unroll
        for (int mt = 0; mt < 2; mt++) {
            int row = qg * 32 + mt * 16 + fr;
            int rc = row < Sv ? row : Sv - 1;
            aq[mt].u = *(const uint4*)(qkv + (base + rc) * 2304 + h * 64 + ks * 32 + fq * 8);
        }
        #pragma unroll
        for (int s = 0; s < 4; s++) {
            int nt = w + 4 * s;
            if (nt >= 14) continue;
            int col = nt * 16 + fr;
            int cc = col < Sv ? col : Sv - 1;
            U bq;
            bq.u = *(const uint4*)(qkv + (base + cc) * 2304 + 768 + h * 64 + ks * 32 + fq * 8);
            #pragma unroll
            for (int mt = 0; mt < 2; mt++)
                sc[mt][s] = __builtin_amdgcn_mfma_f32_16x16x32_bf16(
                    aq[mt].v, bq.v, sc[mt][s], 0, 0, 0);
        }
    }

    // ---- scale + mask + row max ----
    float rmax[2][4];
    #pragma unroll
    for (int mt = 0; mt < 2; mt++)
        #pragma unroll
        for (int r = 0; r < 4; r++) rmax[mt][r] = -1e30f;
    #pragma unroll
    for (int mt = 0; mt < 2; mt++) {
        #pragma unroll
        for (int s = 0; s < 4; s++) {
            int nt = w + 4 * s;
            int col = nt * 16 + fr;
            bool valid = (nt < 14) && (col < Sv);
            #pragma unroll
            for (int r = 0; r < 4; r++) {
                float v = valid ? sc[mt][s][r] * 0.125f : -1e30f;
                sc[mt][s][r] = v;
                rmax[mt][r] = fmaxf(rmax[mt][r], v);
            }
        }
    }
    #pragma unroll
    for (int mt = 0; mt < 2; mt++) {
        #pragma unroll
        for (int r = 0; r < 4; r++) {
            float m = rmax[mt][r];
            m = fmaxf(m, __shfl_xor(m, 1, 64));
            m = fmaxf(m, __shfl_xor(m, 2, 64));
            m = fmaxf(m, __shfl_xor(m, 4, 64));
            m = fmaxf(m, __shfl_xor(m, 8, 64));
            rmax[mt][r] = m;
        }
    }
    if (fr == 0) {
        #pragma unroll
        for (int mt = 0; mt < 2; mt++)
            #pragma unroll
            for (int r = 0; r < 4; r++)
                red[w][mt * 16 + fq * 4 + r] = rmax[mt][r];
    }
    __syncthreads();
    if (tid < 32)
        smax_f[tid] = fmaxf(fmaxf(red[0][tid], red[1][tid]),
                            fmaxf(red[2][tid], red[3][tid]));
    __syncthreads();

    // ---- exp + row sum + write P (bf16, A layout) ----
    float rsum[2][4] = {};
    #pragma unroll
    for (int mt = 0; mt < 2; mt++) {
        float fm[4];
        #pragma unroll
        for (int r = 0; r < 4; r++) fm[r] = smax_f[mt * 16 + fq * 4 + r];
        #pragma unroll
        for (int s = 0; s < 4; s++) {
            int nt = w + 4 * s;
            if (nt >= 14) continue;
            int col = nt * 16 + fr;
            #pragma unroll
            for (int r = 0; r < 4; r++) {
                float p = (col < Sv) ? __expf(sc[mt][s][r] - fm[r]) : 0.f;
                rsum[mt][r] += p;
                pb[mt * 16 + fq * 4 + r][col] = f2bf(p);
            }
        }
    }
    #pragma unroll
    for (int mt = 0; mt < 2; mt++) {
        #pragma unroll
        for (int r = 0; r < 4; r++) {
            float s = rsum[mt][r];
            s += __shfl_xor(s, 1, 64);
            s += __shfl_xor(s, 2, 64);
            s += __shfl_xor(s, 4, 64);
            s += __shfl_xor(s, 8, 64);
            rsum[mt][r] = s;
        }
    }
    if (fr == 0) {
        #pragma unroll
        for (int mt = 0; mt < 2; mt++)
            #pragma unroll
            for (int r = 0; r < 4; r++)
                red[w][mt * 16 + fq * 4 + r] = rsum[mt][r];
    }
    __syncthreads();
    if (tid < 32)
        sinv_f[tid] = 1.f / (red[0][tid] + red[1][tid] + red[2][tid] + red[3][tid]);
    __syncthreads();   // also guarantees vt + pb staging complete

    // ---- PV: wave w -> output dims [w*16, w*16+16) ----
    f32x4 oc[2] = {};
    #pragma unroll
    for (int ks = 0; ks < 7; ks++) {
        U bv;
        bv.u = *(const uint4*)&vt[w * 16 + fr][ks * 32 + fq * 8];
        #pragma unroll
        for (int mt = 0; mt < 2; mt++) {
            const unsigned short* ap = &pb[mt * 16 + fr][ks * 32 + fq * 8];
            uint2 lo = *(const uint2*)ap;
            uint2 hi = *(const uint2*)(ap + 4);
            U a; a.u = make_uint4(lo.x, lo.y, hi.x, hi.y);
            oc[mt] = __builtin_amdgcn_mfma_f32_16x16x32_bf16(a.v, bv.v, oc[mt], 0, 0, 0);
        }
    }

    // ---- epilogue: /= rowsum, store bf16 ----
    #pragma unroll
    for (int mt = 0; mt < 2; mt++) {
        #pragma unroll
        for (int r = 0; r < 4; r++) {
            int lrow = mt * 16 + fq * 4 + r;
            int row = qg * 32 + lrow;
            if (row < Sv)
                o[(base + row) * Dv + h * 64 + w * 16 + fr] =
                    f2bf(oc[mt][r] * sinv_f[lrow]);
        }
    }
}

// ---------------------------------------------------------------------------
// Head: ln_post on cls token + @ vis_proj [768,512] fp32. One block per batch.
// ---------------------------------------------------------------------------
__global__ void head_kernel(const float* __restrict__ x,
                            const float* __restrict__ s, const float* __restrict__ b,
                            const float* __restrict__ vp, float* __restrict__ out) {
    int bb = blockIdx.x, tid = threadIdx.x;
    __shared__ float xn[Dv];
    const float* row = x + (size_t)(bb * Sv) * Dv;
    float v[3], s1 = 0.f, s2 = 0.f;
    #pragma unroll
    for (int i = 0; i < 3; i++) {
        v[i] = row[tid + 256 * i];
        s1 += v[i]; s2 += v[i] * v[i];
    }
    reduce2_256(s1, s2);
    float mean = s1 * (1.0f / Dv);
    float var  = s2 * (1.0f / Dv) - mean * mean;
    float rstd = rsqrtf(var + 1e-5f);
    #pragma unroll
    for (int i = 0; i < 3; i++) {
        int d = tid + 256 * i;
        xn[d] = (v[i] - mean) * rstd * s[d] + b[d];
    }
    __syncthreads();
    float acc0 = 0.f, acc1 = 0.f;
    for (int d = 0; d < Dv; d++) {
        float xv = xn[d];
        acc0 += xv * vp[(size_t)d * Ov + tid];
        acc1 += xv * vp[(size_t)d * Ov + tid + 256];
    }
    out[(size_t)bb * Ov + tid]       = acc0;
    out[(size_t)bb * Ov + tid + 256] = acc1;
}

// ---------------------------------------------------------------------------
extern "C" void kernel_launch(void* const* d_in, const int* in_sizes, int n_in,
                              void* d_out, int out_size, void* d_ws, size_t ws_size,
                              hipStream_t stream) {
    const float* images   = (const float*)d_in[0];
    const float* conv_w   = (const float*)d_in[1];
    const float* cls_emb  = (const float*)d_in[2];
    const float* pos_emb  = (const float*)d_in[3];
    const float* lnpre_s  = (const float*)d_in[4];
    const float* lnpre_b  = (const float*)d_in[5];
    const float* ln1_s    = (const float*)d_in[6];
    const float* ln1_b    = (const float*)d_in[7];
    const float* qkv_w    = (const float*)d_in[8];
    const float* qkv_b    = (const float*)d_in[9];
    const float* out_w    = (const float*)d_in[10];
    const float* out_b    = (const float*)d_in[11];
    const float* ln2_s    = (const float*)d_in[12];
    const float* ln2_b    = (const float*)d_in[13];
    const float* fc_w     = (const float*)d_in[14];
    const float* fc_b     = (const float*)d_in[15];
    const float* proj_w   = (const float*)d_in[16];
    const float* proj_b   = (const float*)d_in[17];
    const float* lnpost_s = (const float*)d_in[18];
    const float* lnpost_b = (const float*)d_in[19];
    const float* vis_proj = (const float*)d_in[20];
    float* out = (float*)d_out;

    char* p = (char*)d_ws;
    float* x              = (float*)p;          p += (size_t)TOK * Dv * 4;       // 19.4 MB
    unsigned short* abuf  = (unsigned short*)p; p += (size_t)MPAD * Dv * 2;      //  9.8 MB
    unsigned short* qkvb  = (unsigned short*)p; p += (size_t)MPAD * 2304 * 2;    // 29.5 MB
    unsigned short* hbuf  = (unsigned short*)p; p += (size_t)MPAD * Fv * 2;      // 39.3 MB
    unsigned short* wbuf  = (unsigned short*)p; p += (size_t)WTOT * 2;           // 14.2 MB
    unsigned short* cwb   = (unsigned short*)p; p += (size_t)WO_SZ * 2;          //  1.2 MB
    // aliases (pre-loop only):
    unsigned short* im2c  = qkvb;               // [6272,768] bf16 (rows to 6400 readable)
    float* convo          = (float*)hbuf;       // [6272,768] fp32

    const int GY = MPAD / 256;   // 25 row-tiles (covers conv's 6272 too)

    // patch embedding
    convert_kernel<<<WO_SZ / 4 / 256, 256, 0, stream>>>(conv_w, cwb, WO_SZ / 4);
    im2col_kernel<<<(CONV_M * Dv) / 256, 256, 0, stream>>>(images, im2c);
    gemm_mfma<0, 0, 256><<<dim3(Dv / 256, GY, 1), 512, 0, stream>>>(
        im2c, cwb, nullptr, nullptr, convo, CONV_M, Dv, Dv);
    embed_ln_kernel<<<TOK, 256, 0, stream>>>(convo, cls_emb, pos_emb,
                                             lnpre_s, lnpre_b, x);

    unsigned short* wq = wbuf;
    unsigned short* wo = wbuf + WQ_SZ;
    unsigned short* wf = wbuf + WQ_SZ + WO_SZ;
    unsigned short* wp = wbuf + WQ_SZ + WO_SZ + WF_SZ;

    for (int l = 0; l < Lv; l++) {
        convertw_kernel<<<WTOT / 4 / 256, 256, 0, stream>>>(
            qkv_w + (size_t)l * WQ_SZ, out_w + (size_t)l * WO_SZ,
            fc_w + (size_t)l * WF_SZ, proj_w + (size_t)l * WP_SZ, wbuf);
        ln_kernel<<<TOK, 256, 0, stream>>>(x, abuf, ln1_s + l * Dv, ln1_b + l * Dv);
        gemm_mfma<1, 0, 256><<<dim3(2304 / 256, GY, 1), 512, 0, stream>>>(
            abuf, wq, qkv_b + (size_t)l * 2304, nullptr, qkvb, TOK, 2304, Dv);
        attn4_kernel<<<dim3(7, Hh, Bv), 256, 0, stream>>>(qkvb, abuf);
        // out_proj: 256x128, split-K=2 (300 blocks), atomicAdd into x
        gemm_mfma<2, 0, 128><<<dim3(Dv / 128, GY, 2), 512, 0, stream>>>(
            abuf, wo, out_b + (size_t)l * Dv, nullptr, x, TOK, Dv, Dv);
        ln_kernel<<<TOK, 256, 0, stream>>>(x, abuf, ln2_s + l * Dv, ln2_b + l * Dv);
        gemm_mfma<1, 1, 256><<<dim3(Fv / 256, GY, 1), 512, 0, stream>>>(
            abuf, wf, fc_b + (size_t)l * Fv, nullptr, hbuf, TOK, Fv, Dv);
        // mlp proj: 256x128, split-K=2 (300 blocks), atomicAdd into x
        gemm_mfma<2, 0, 128><<<dim3(Dv / 128, GY, 2), 512, 0, stream>>>(
            hbuf, wp, proj_b + (size_t)l * Dv, nullptr, x, TOK, Dv, Fv);
    }

    head_kernel<<<Bv, 256, 0, stream>>>(x, lnpost_s, lnpost_b, vis_proj, out);
}

// Round 9
// 4140.277 us; speedup vs baseline: 1.5733x; 1.0595x over previous
//
#include <hip/hip_runtime.h>
#include <cstddef>

#define Bv   32
#define Sv   197
#define Dv   768
#define Hh   12
#define HDv  64
#define Fv   3072
#define Lv   12
#define Ov   512
#define TOK  (Bv * Sv)        // 6304
#define MPAD 6400             // TOK padded (multiple of 256: 25*256)
#define NPATCH 196
#define CONV_M (Bv * NPATCH)  // 6272

#define WQ_SZ (2304 * 768)
#define WO_SZ (768 * 768)
#define WF_SZ (3072 * 768)
#define WP_SZ (768 * 3072)
#define WTOT  (WQ_SZ + WO_SZ + WF_SZ + WP_SZ)   // 7077888

typedef __attribute__((ext_vector_type(8))) __bf16 bf16x8;
typedef __attribute__((ext_vector_type(4))) float f32x4;

__device__ __forceinline__ unsigned short f2bf(float f) {
    unsigned int u = __float_as_uint(f);
    unsigned int r = (u + 0x7fffu + ((u >> 16) & 1u)) >> 16;
    return (unsigned short)r;
}

__device__ __forceinline__ void async_ld16(const void* g, void* l) {
    __builtin_amdgcn_global_load_lds(
        (__attribute__((address_space(1))) void*)(g),
        (__attribute__((address_space(3))) void*)(l),
        16, 0, 0);
}

// ---------------------------------------------------------------------------
// block-wide (256 thread) reduction of two scalars
// ---------------------------------------------------------------------------
__device__ __forceinline__ void reduce2_256(float& s1, float& s2) {
    #pragma unroll
    for (int off = 32; off > 0; off >>= 1) {
        s1 += __shfl_down(s1, off, 64);
        s2 += __shfl_down(s2, off, 64);
    }
    __shared__ float r1[4], r2[4];
    int lane = threadIdx.x & 63, w = threadIdx.x >> 6;
    if (lane == 0) { r1[w] = s1; r2[w] = s2; }
    __syncthreads();
    s1 = r1[0] + r1[1] + r1[2] + r1[3];
    s2 = r2[0] + r2[1] + r2[2] + r2[3];
    __syncthreads();
}

// ---------------------------------------------------------------------------
// weight fp32 -> bf16 conversion
// ---------------------------------------------------------------------------
__global__ void convert_kernel(const float* __restrict__ src,
                               unsigned short* __restrict__ dst, int n4) {
    int gid = blockIdx.x * 256 + threadIdx.x;
    if (gid >= n4) return;
    int idx = gid * 4;
    float4 v = *(const float4*)(src + idx);
    ushort4 r = make_ushort4(f2bf(v.x), f2bf(v.y), f2bf(v.z), f2bf(v.w));
    *(ushort4*)(dst + idx) = r;
}

__global__ void convertw_kernel(const float* __restrict__ wq,
                                const float* __restrict__ wo,
                                const float* __restrict__ wf,
                                const float* __restrict__ wp,
                                unsigned short* __restrict__ dst) {
    int idx = (blockIdx.x * 256 + threadIdx.x) * 4;
    const float* s; int off;
    if (idx < WQ_SZ)                     { s = wq; off = idx; }
    else if (idx < WQ_SZ + WO_SZ)        { s = wo; off = idx - WQ_SZ; }
    else if (idx < WQ_SZ + WO_SZ + WF_SZ){ s = wf; off = idx - WQ_SZ - WO_SZ; }
    else                                 { s = wp; off = idx - WQ_SZ - WO_SZ - WF_SZ; }
    float4 v = *(const float4*)(s + off);
    ushort4 r = make_ushort4(f2bf(v.x), f2bf(v.y), f2bf(v.z), f2bf(v.w));
    *(ushort4*)(dst + idx) = r;
}

// ---------------------------------------------------------------------------
// im2col + normalize -> bf16 patches [6272, 768]
// ---------------------------------------------------------------------------
__global__ void im2col_kernel(const float* __restrict__ img,
                              unsigned short* __restrict__ out) {
    int idx = blockIdx.x * 256 + threadIdx.x;
    int col = idx % 768;
    int row = idx / 768;
    int b = row / NPATCH, p = row % NPATCH;
    int ph = p / 14, pw = p % 14;
    int c  = col >> 8;
    int r  = col & 255;
    int kh = r >> 4, kw = r & 15;
    int y = ph * 16 + kh, x = pw * 16 + kw;
    const float mean[3] = {0.48145466f, 0.4578275f, 0.40821073f};
    const float stdv[3] = {0.26862954f, 0.26130258f, 0.27577711f};
    float v = img[((size_t)(b * 3 + c) * 224 + y) * 224 + x];
    out[idx] = f2bf((v - mean[c]) / stdv[c]);
}

// ---------------------------------------------------------------------------
// MFMA bf16 GEMM: C[m,n] = sum_k A[m,k]*W[n,k] (+bias) (+res fp32) (QuickGELU)
// v10: BM=256, BN template (256 or 128), BK=64, 512 threads (8 waves).
//  Law (r0-r8): time ~= rounds x (per_block_staged_bytes / 24 GB/s/CU)
//               + atomic_MB x ~1us;  rounds = ceil(blocks / resident_cap).
//  At 128 KB LDS -> 1 block/CU, so grids must be <= 256 for one clean round:
//  - qkv/fc/conv: BN=256 (grids 225/300/75)      [r7-validated]
//  - out/proj:    BN=256 + split-K=2 -> 150 blocks, ONE round
//                 (r8's BN=128/300-blk had a 2-round tail -> 119us; this
//                  config: proj 1 x 1.57MB/blk ~ 65us + 38MB atomics)
//  - staging/read XOR swizzle verbatim from r3/r7 (SQ_LDS_BANK_CONFLICT=0).
//  - split-K via gridDim.z: ODT==2 -> fp32 atomicAdd into C (C pre-holds
//    residual; bias added by z==0 block only).
//  - XCD-aware bijective remap kept.
// ---------------------------------------------------------------------------
template<int ODT, int ACT, int BN>
__global__ __launch_bounds__(512) void gemm_mfma(
        const unsigned short* __restrict__ A, const unsigned short* __restrict__ W,
        const float* __restrict__ bias, const float* __restrict__ res,
        void* __restrict__ Cv, int M, int N, int K)
{
    constexpr int WN = (BN == 256) ? 4 : 2;   // waves along N
    constexpr int WM = 8 / WN;                // waves along M
    constexpr int MI = 256 / WM / 16;         // A-fragments per wave (8 or 4)
    constexpr int NI = BN / WN / 16;          // W-fragments per wave (4)
    constexpr int NWI = BN / 64;              // W stage instrs (4 or 2)

    __shared__ unsigned short As[2][256 * 64];
    __shared__ unsigned short Ws[2][BN * 64];
    const int tid = threadIdx.x;
    const int w = tid >> 6, l = tid & 63;

    // ---- XCD-aware bijective remap of linear workgroup id (T1, m204) ----
    const int gx = gridDim.x;
    const int wg  = blockIdx.y * gx + blockIdx.x;
    const int nwg = gx * gridDim.y;
    const int q = nwg >> 3, r8 = nwg & 7;
    const int xcd = wg & 7, lo = wg >> 3;
    const int swz = (xcd < r8 ? xcd * (q + 1) : r8 * (q + 1) + (xcd - r8) * q) + lo;
    const int m0 = (swz / gx) << 8;      // 256-row tile
    const int n0 = (swz % gx) * BN;      // BN-col tile

    // ---- split-K ----
    const int kseg  = K / gridDim.z;
    const int kbase = blockIdx.z * kseg;

    // ---- staging (r3-verified): pre-swizzled global src, linear LDS dest ----
    // per instr: 64 lanes x 16B = 1 KB = 8 rows x 64 cols(bf16).
    // lane l -> row l>>3, src 16B-chunk (l&7)^(l>>3); wave w instr i covers
    // rows [w*8 + i*64, +8).
    const int lrow = l >> 3;
    const int lchk = (l & 7) ^ lrow;
    const unsigned short* agp = A + (size_t)(m0 + w * 8 + lrow) * K + kbase + lchk * 8;
    const unsigned short* wgp = W + (size_t)(n0 + w * 8 + lrow) * K + kbase + lchk * 8;
    const int lbase = (w * 8) * 64;      // shorts; + i*64*64 per instr

    // ---- fragment read offsets (swizzled; r3-verified pattern) ----
    const int wm = w / WN, wn = w % WN;
    const int fr = l & 15, fq = l >> 4;
    int aoff[2][MI], woff[2][NI];
    #pragma unroll
    for (int ks = 0; ks < 2; ks++) {
        const int pc = ((ks * 4 + fq) ^ (fr & 7)) * 8;
        #pragma unroll
        for (int i = 0; i < MI; i++)
            aoff[ks][i] = (wm * (MI * 16) + i * 16 + fr) * 64 + pc;
        #pragma unroll
        for (int j = 0; j < NI; j++)
            woff[ks][j] = (wn * (NI * 16) + j * 16 + fr) * 64 + pc;
    }

    f32x4 acc[MI][NI] = {};
    const int nt = kseg >> 6;   // BK=64

    #define STAGE(t, bf) do {                                              \
        const int _ko = (t) << 6;                                          \
        _Pragma("unroll")                                                  \
        for (int _i = 0; _i < 4; _i++)                                     \
            async_ld16(agp + (size_t)_i * 64 * K + _ko,                    \
                       &As[bf][lbase + _i * 64 * 64]);                     \
        _Pragma("unroll")                                                  \
        for (int _i = 0; _i < NWI; _i++)                                   \
            async_ld16(wgp + (size_t)_i * 64 * K + _ko,                    \
                       &Ws[bf][lbase + _i * 64 * 64]);                     \
    } while (0)

    auto compute = [&](const unsigned short* ab, const unsigned short* wb) {
        #pragma unroll
        for (int ks = 0; ks < 2; ks++) {
            bf16x8 wf[NI];
            #pragma unroll
            for (int j = 0; j < NI; j++)
                wf[j] = *(const bf16x8*)(wb + woff[ks][j]);
            #pragma unroll
            for (int i = 0; i < MI; i++) {
                bf16x8 af = *(const bf16x8*)(ab + aoff[ks][i]);
                #pragma unroll
                for (int j = 0; j < NI; j++) {
                    acc[i][j] = __builtin_amdgcn_mfma_f32_16x16x32_bf16(
                        af, wf[j], acc[i][j], 0, 0, 0);
                }
            }
        }
    };

    // prologue
    STAGE(0, 0);
    __syncthreads();

    int bf = 0;
    for (int t = 0; t < nt; t++) {
        if (t + 1 < nt) STAGE(t + 1, bf ^ 1);
        compute(As[bf], Ws[bf]);
        __syncthreads();        // staged t+1 landed; all reads of bf consumed
        bf ^= 1;
    }
    #undef STAGE

    const bool addb = (ODT != 2) || (blockIdx.z == 0);
    float bn[NI];
    #pragma unroll
    for (int j = 0; j < NI; j++)
        bn[j] = (bias && addb) ? bias[n0 + wn * (NI * 16) + j * 16 + fr] : 0.f;

    #pragma unroll
    for (int i = 0; i < MI; i++) {
        #pragma unroll
        for (int r = 0; r < 4; r++) {
            int m = m0 + wm * (MI * 16) + i * 16 + fq * 4 + r;
            if (m < M) {
                size_t rowb = (size_t)m * N;
                #pragma unroll
                for (int j = 0; j < NI; j++) {
                    int n = n0 + wn * (NI * 16) + j * 16 + fr;
                    float v = acc[i][j][r] + bn[j];
                    if (ODT == 2) {
                        atomicAdd((float*)Cv + rowb + n, v);
                    } else {
                        if (res) v += res[rowb + n];
                        if (ACT) v = v / (1.f + __expf(-1.702f * v));
                        if (ODT == 0) ((float*)Cv)[rowb + n] = v;
                        else ((unsigned short*)Cv)[rowb + n] = f2bf(v);
                    }
                }
            }
        }
    }
}

// ---------------------------------------------------------------------------
// LayerNorm fp32 in -> bf16 out. One block per token.
// ---------------------------------------------------------------------------
__global__ void ln_kernel(const float* __restrict__ in, unsigned short* __restrict__ out,
                          const float* __restrict__ s, const float* __restrict__ b) {
    int t = blockIdx.x;
    const float* row = in + (size_t)t * Dv;
    int tid = threadIdx.x;
    float v[3], s1 = 0.f, s2 = 0.f;
    #pragma unroll
    for (int i = 0; i < 3; i++) {
        v[i] = row[tid + 256 * i];
        s1 += v[i]; s2 += v[i] * v[i];
    }
    reduce2_256(s1, s2);
    float mean = s1 * (1.0f / Dv);
    float var  = s2 * (1.0f / Dv) - mean * mean;
    float rstd = rsqrtf(var + 1e-5f);
    unsigned short* orow = out + (size_t)t * Dv;
    #pragma unroll
    for (int i = 0; i < 3; i++) {
        int d = tid + 256 * i;
        orow[d] = f2bf((v[i] - mean) * rstd * s[d] + b[d]);
    }
}

// ---------------------------------------------------------------------------
// embed (cls/patch + pos) + ln_pre -> x fp32. One block per token.
// ---------------------------------------------------------------------------
__global__ void embed_ln_kernel(const float* __restrict__ conv_out,
                                const float* __restrict__ cls,
                                const float* __restrict__ pos,
                                const float* __restrict__ s,
                                const float* __restrict__ b,
                                float* __restrict__ x) {
    int t = blockIdx.x;
    int bb = t / Sv, si = t % Sv;
    int tid = threadIdx.x;
    float v[3], s1 = 0.f, s2 = 0.f;
    #pragma unroll
    for (int i = 0; i < 3; i++) {
        int d = tid + 256 * i;
        float e = (si == 0) ? cls[d]
                            : conv_out[((size_t)bb * NPATCH + (si - 1)) * Dv + d];
        v[i] = e + pos[(size_t)si * Dv + d];
        s1 += v[i]; s2 += v[i] * v[i];
    }
    reduce2_256(s1, s2);
    float mean = s1 * (1.0f / Dv);
    float var  = s2 * (1.0f / Dv) - mean * mean;
    float rstd = rsqrtf(var + 1e-5f);
    float* orow = x + (size_t)t * Dv;
    #pragma unroll
    for (int i = 0; i < 3; i++) {
        int d = tid + 256 * i;
        orow[d] = (v[i] - mean) * rstd * s[d] + b[d];
    }
}

// ---------------------------------------------------------------------------
// Attention v4 (MFMA): grid (7, H, B); block = 256 thr = 4 waves; 32 q-rows.
// ---------------------------------------------------------------------------
__global__ __launch_bounds__(256) void attn4_kernel(
        const unsigned short* __restrict__ qkv, unsigned short* __restrict__ o) {
    const int qg = blockIdx.x, h = blockIdx.y, b = blockIdx.z;
    __shared__ __align__(16) unsigned short vt[64][232];   // V^T [d][j], 29.7 KB
    __shared__ __align__(16) unsigned short pb[32][236];   // P bf16 [row][k], 14.8 KB
    __shared__ float red[4][32];
    __shared__ float smax_f[32];
    __shared__ float sinv_f[32];

    const int tid = threadIdx.x;
    const int w = tid >> 6, l = tid & 63;
    const int fr = l & 15, fq = l >> 4;
    const size_t base = (size_t)b * Sv;
    const unsigned int* q32 = (const unsigned int*)qkv;    // row stride 1152 uints

    // ---- stage V^T (cols >= 197 zeroed) ----
    for (int i = tid; i < 224 * 32; i += 256) {
        int j = i >> 5, u = i & 31;
        unsigned int val = (j < Sv) ? q32[(base + j) * 1152 + 768 + h * 32 + u] : 0u;
        vt[2 * u][j]     = (unsigned short)(val & 0xffffu);
        vt[2 * u + 1][j] = (unsigned short)(val >> 16);
    }

    union U { uint4 u; bf16x8 v; };

    // ---- QK^T: sc[mt][s], rows qg*32+mt*16+fq*4+r, cols (w+4s)*16+fr ----
    f32x4 sc[2][4] = {};
    #pragma unroll
    for (int ks = 0; ks < 2; ks++) {
        U aq[2];
        #pragma unroll
        for (int mt = 0; mt < 2; mt++) {
            int row = qg * 32 + mt * 16 + fr;
            int rc = row < Sv ? row : Sv - 1;
            aq[mt].u = *(const uint4*)(qkv + (base + rc) * 2304 + h * 64 + ks * 32 + fq * 8);
        }
        #pragma unroll
        for (int s = 0; s < 4; s++) {
            int nt = w + 4 * s;
            if (nt >= 14) continue;
            int col = nt * 16 + fr;
            int cc = col < Sv ? col : Sv - 1;
            U bq;
            bq.u = *(const uint4*)(qkv + (base + cc) * 2304 + 768 + h * 64 + ks * 32 + fq * 8);
            #pragma unroll
            for (int mt = 0; mt < 2; mt++)
                sc[mt][s] = __builtin_amdgcn_mfma_f32_16x16x32_bf16(
                    aq[mt].v, bq.v, sc[mt][s], 0, 0, 0);
        }
    }

    // ---- scale + mask + row max ----
    float rmax[2][4];
    #pragma unroll
    for (int mt = 0; mt < 2; mt++)
        #pragma unroll
        for (int r = 0; r < 4; r++) rmax[mt][r] = -1e30f;
    #pragma unroll
    for (int mt = 0; mt < 2; mt++) {
        #pragma unroll
        for (int s = 0; s < 4; s++) {
            int nt = w + 4 * s;
            int col = nt * 16 + fr;
            bool valid = (nt < 14) && (col < Sv);
            #pragma unroll
            for (int r = 0; r < 4; r++) {
                float v = valid ? sc[mt][s][r] * 0.125f : -1e30f;
                sc[mt][s][r] = v;
                rmax[mt][r] = fmaxf(rmax[mt][r], v);
            }
        }
    }
    #pragma unroll
    for (int mt = 0; mt < 2; mt++) {
        #pragma unroll
        for (int r = 0; r < 4; r++) {
            float m = rmax[mt][r];
            m = fmaxf(m, __shfl_xor(m, 1, 64));
            m = fmaxf(m, __shfl_xor(m, 2, 64));
            m = fmaxf(m, __shfl_xor(m, 4, 64));
            m = fmaxf(m, __shfl_xor(m, 8, 64));
            rmax[mt][r] = m;
        }
    }
    if (fr == 0) {
        #pragma unroll
        for (int mt = 0; mt < 2; mt++)
            #pragma unroll
            for (int r = 0; r < 4; r++)
                red[w][mt * 16 + fq * 4 + r] = rmax[mt][r];
    }
    __syncthreads();
    if (tid < 32)
        smax_f[tid] = fmaxf(fmaxf(red[0][tid], red[1][tid]),
                            fmaxf(red[2][tid], red[3][tid]));
    __syncthreads();

    // ---- exp + row sum + write P (bf16, A layout) ----
    float rsum[2][4] = {};
    #pragma unroll
    for (int mt = 0; mt < 2; mt++) {
        float fm[4];
        #pragma unroll
        for (int r = 0; r < 4; r++) fm[r] = smax_f[mt * 16 + fq * 4 + r];
        #pragma unroll
        for (int s = 0; s < 4; s++) {
            int nt = w + 4 * s;
            if (nt >= 14) continue;
            int col = nt * 16 + fr;
            #pragma unroll
            for (int r = 0; r < 4; r++) {
                float p = (col < Sv) ? __expf(sc[mt][s][r] - fm[r]) : 0.f;
                rsum[mt][r] += p;
                pb[mt * 16 + fq * 4 + r][col] = f2bf(p);
            }
        }
    }
    #pragma unroll
    for (int mt = 0; mt < 2; mt++) {
        #pragma unroll
        for (int r = 0; r < 4; r++) {
            float s = rsum[mt][r];
            s += __shfl_xor(s, 1, 64);
            s += __shfl_xor(s, 2, 64);
            s += __shfl_xor(s, 4, 64);
            s += __shfl_xor(s, 8, 64);
            rsum[mt][r] = s;
        }
    }
    if (fr == 0) {
        #pragma unroll
        for (int mt = 0; mt < 2; mt++)
            #pragma unroll
            for (int r = 0; r < 4; r++)
                red[w][mt * 16 + fq * 4 + r] = rsum[mt][r];
    }
    __syncthreads();
    if (tid < 32)
        sinv_f[tid] = 1.f / (red[0][tid] + red[1][tid] + red[2][tid] + red[3][tid]);
    __syncthreads();   // also guarantees vt + pb staging complete

    // ---- PV: wave w -> output dims [w*16, w*16+16) ----
    f32x4 oc[2] = {};
    #pragma unroll
    for (int ks = 0; ks < 7; ks++) {
        U bv;
        bv.u = *(const uint4*)&vt[w * 16 + fr][ks * 32 + fq * 8];
        #pragma unroll
        for (int mt = 0; mt < 2; mt++) {
            const unsigned short* ap = &pb[mt * 16 + fr][ks * 32 + fq * 8];
            uint2 lo = *(const uint2*)ap;
            uint2 hi = *(const uint2*)(ap + 4);
            U a; a.u = make_uint4(lo.x, lo.y, hi.x, hi.y);
            oc[mt] = __builtin_amdgcn_mfma_f32_16x16x32_bf16(a.v, bv.v, oc[mt], 0, 0, 0);
        }
    }

    // ---- epilogue: /= rowsum, store bf16 ----
    #pragma unroll
    for (int mt = 0; mt < 2; mt++) {
        #pragma unroll
        for (int r = 0; r < 4; r++) {
            int lrow = mt * 16 + fq * 4 + r;
            int row = qg * 32 + lrow;
            if (row < Sv)
                o[(base + row) * Dv + h * 64 + w * 16 + fr] =
                    f2bf(oc[mt][r] * sinv_f[lrow]);
        }
    }
}

// ---------------------------------------------------------------------------
// Head: ln_post on cls token + @ vis_proj [768,512] fp32. One block per batch.
// ---------------------------------------------------------------------------
__global__ void head_kernel(const float* __restrict__ x,
                            const float* __restrict__ s, const float* __restrict__ b,
                            const float* __restrict__ vp, float* __restrict__ out) {
    int bb = blockIdx.x, tid = threadIdx.x;
    __shared__ float xn[Dv];
    const float* row = x + (size_t)(bb * Sv) * Dv;
    float v[3], s1 = 0.f, s2 = 0.f;
    #pragma unroll
    for (int i = 0; i < 3; i++) {
        v[i] = row[tid + 256 * i];
        s1 += v[i]; s2 += v[i] * v[i];
    }
    reduce2_256(s1, s2);
    float mean = s1 * (1.0f / Dv);
    float var  = s2 * (1.0f / Dv) - mean * mean;
    float rstd = rsqrtf(var + 1e-5f);
    #pragma unroll
    for (int i = 0; i < 3; i++) {
        int d = tid + 256 * i;
        xn[d] = (v[i] - mean) * rstd * s[d] + b[d];
    }
    __syncthreads();
    float acc0 = 0.f, acc1 = 0.f;
    for (int d = 0; d < Dv; d++) {
        float xv = xn[d];
        acc0 += xv * vp[(size_t)d * Ov + tid];
        acc1 += xv * vp[(size_t)d * Ov + tid + 256];
    }
    out[(size_t)bb * Ov + tid]       = acc0;
    out[(size_t)bb * Ov + tid + 256] = acc1;
}

// ---------------------------------------------------------------------------
extern "C" void kernel_launch(void* const* d_in, const int* in_sizes, int n_in,
                              void* d_out, int out_size, void* d_ws, size_t ws_size,
                              hipStream_t stream) {
    const float* images   = (const float*)d_in[0];
    const float* conv_w   = (const float*)d_in[1];
    const float* cls_emb  = (const float*)d_in[2];
    const float* pos_emb  = (const float*)d_in[3];
    const float* lnpre_s  = (const float*)d_in[4];
    const float* lnpre_b  = (const float*)d_in[5];
    const float* ln1_s    = (const float*)d_in[6];
    const float* ln1_b    = (const float*)d_in[7];
    const float* qkv_w    = (const float*)d_in[8];
    const float* qkv_b    = (const float*)d_in[9];
    const float* out_w    = (const float*)d_in[10];
    const float* out_b    = (const float*)d_in[11];
    const float* ln2_s    = (const float*)d_in[12];
    const float* ln2_b    = (const float*)d_in[13];
    const float* fc_w     = (const float*)d_in[14];
    const float* fc_b     = (const float*)d_in[15];
    const float* proj_w   = (const float*)d_in[16];
    const float* proj_b   = (const float*)d_in[17];
    const float* lnpost_s = (const float*)d_in[18];
    const float* lnpost_b = (const float*)d_in[19];
    const float* vis_proj = (const float*)d_in[20];
    float* out = (float*)d_out;

    char* p = (char*)d_ws;
    float* x              = (float*)p;          p += (size_t)TOK * Dv * 4;       // 19.4 MB
    unsigned short* abuf  = (unsigned short*)p; p += (size_t)MPAD * Dv * 2;      //  9.8 MB
    unsigned short* qkvb  = (unsigned short*)p; p += (size_t)MPAD * 2304 * 2;    // 29.5 MB
    unsigned short* hbuf  = (unsigned short*)p; p += (size_t)MPAD * Fv * 2;      // 39.3 MB
    unsigned short* wbuf  = (unsigned short*)p; p += (size_t)WTOT * 2;           // 14.2 MB
    unsigned short* cwb   = (unsigned short*)p; p += (size_t)WO_SZ * 2;          //  1.2 MB
    // aliases (pre-loop only):
    unsigned short* im2c  = qkvb;               // [6272,768] bf16 (rows to 6400 readable)
    float* convo          = (float*)hbuf;       // [6272,768] fp32

    const int GY = MPAD / 256;   // 25 row-tiles (covers conv's 6272 too)

    // patch embedding
    convert_kernel<<<WO_SZ / 4 / 256, 256, 0, stream>>>(conv_w, cwb, WO_SZ / 4);
    im2col_kernel<<<(CONV_M * Dv) / 256, 256, 0, stream>>>(images, im2c);
    gemm_mfma<0, 0, 256><<<dim3(Dv / 256, GY, 1), 512, 0, stream>>>(
        im2c, cwb, nullptr, nullptr, convo, CONV_M, Dv, Dv);
    embed_ln_kernel<<<TOK, 256, 0, stream>>>(convo, cls_emb, pos_emb,
                                             lnpre_s, lnpre_b, x);

    unsigned short* wq = wbuf;
    unsigned short* wo = wbuf + WQ_SZ;
    unsigned short* wf = wbuf + WQ_SZ + WO_SZ;
    unsigned short* wp = wbuf + WQ_SZ + WO_SZ + WF_SZ;

    for (int l = 0; l < Lv; l++) {
        convertw_kernel<<<WTOT / 4 / 256, 256, 0, stream>>>(
            qkv_w + (size_t)l * WQ_SZ, out_w + (size_t)l * WO_SZ,
            fc_w + (size_t)l * WF_SZ, proj_w + (size_t)l * WP_SZ, wbuf);
        ln_kernel<<<TOK, 256, 0, stream>>>(x, abuf, ln1_s + l * Dv, ln1_b + l * Dv);
        gemm_mfma<1, 0, 256><<<dim3(2304 / 256, GY, 1), 512, 0, stream>>>(
            abuf, wq, qkv_b + (size_t)l * 2304, nullptr, qkvb, TOK, 2304, Dv);
        attn4_kernel<<<dim3(7, Hh, Bv), 256, 0, stream>>>(qkvb, abuf);
        // out_proj: 256x256, split-K=2 -> 150 blocks, ONE round, atomics into x
        gemm_mfma<2, 0, 256><<<dim3(Dv / 256, GY, 2), 512, 0, stream>>>(
            abuf, wo, out_b + (size_t)l * Dv, nullptr, x, TOK, Dv, Dv);
        ln_kernel<<<TOK, 256, 0, stream>>>(x, abuf, ln2_s + l * Dv, ln2_b + l * Dv);
        gemm_mfma<1, 1, 256><<<dim3(Fv / 256, GY, 1), 512, 0, stream>>>(
            abuf, wf, fc_b + (size_t)l * Fv, nullptr, hbuf, TOK, Fv, Dv);
        // mlp proj: 256x256, split-K=2 -> 150 blocks, ONE round, atomics into x
        gemm_mfma<2, 0, 256><<<dim3(Dv / 256, GY, 2), 512, 0, stream>>>(
            hbuf, wp, proj_b + (size_t)l * Dv, nullptr, x, TOK, Dv, Fv);
    }

    head_kernel<<<Bv, 256, 0, stream>>>(x, lnpost_s, lnpost_b, vis_proj, out);
}

// Round 10
// 4123.314 us; speedup vs baseline: 1.5798x; 1.0041x over previous
//
#include <hip/hip_runtime.h>
#include <cstddef>

#define Bv   32
#define Sv   197
#define Dv   768
#define Hh   12
#define HDv  64
#define Fv   3072
#define Lv   12
#define Ov   512
#define TOK  (Bv * Sv)        // 6304
#define MPAD 6400             // TOK padded (multiple of 256: 25*256)
#define NPATCH 196
#define CONV_M (Bv * NPATCH)  // 6272

#define WQ_SZ (2304 * 768)
#define WO_SZ (768 * 768)
#define WF_SZ (3072 * 768)
#define WP_SZ (768 * 3072)
#define WTOT  (WQ_SZ + WO_SZ + WF_SZ + WP_SZ)   // 7077888

typedef __attribute__((ext_vector_type(8))) __bf16 bf16x8;
typedef __attribute__((ext_vector_type(4))) float f32x4;

__device__ __forceinline__ unsigned short f2bf(float f) {
    unsigned int u = __float_as_uint(f);
    unsigned int r = (u + 0x7fffu + ((u >> 16) & 1u)) >> 16;
    return (unsigned short)r;
}

__device__ __forceinline__ void async_ld16(const void* g, void* l) {
    __builtin_amdgcn_global_load_lds(
        (__attribute__((address_space(1))) void*)(g),
        (__attribute__((address_space(3))) void*)(l),
        16, 0, 0);
}

// ---------------------------------------------------------------------------
// block-wide (256 thread) reduction of two scalars
// ---------------------------------------------------------------------------
__device__ __forceinline__ void reduce2_256(float& s1, float& s2) {
    #pragma unroll
    for (int off = 32; off > 0; off >>= 1) {
        s1 += __shfl_down(s1, off, 64);
        s2 += __shfl_down(s2, off, 64);
    }
    __shared__ float r1[4], r2[4];
    int lane = threadIdx.x & 63, w = threadIdx.x >> 6;
    if (lane == 0) { r1[w] = s1; r2[w] = s2; }
    __syncthreads();
    s1 = r1[0] + r1[1] + r1[2] + r1[3];
    s2 = r2[0] + r2[1] + r2[2] + r2[3];
    __syncthreads();
}

// ---------------------------------------------------------------------------
// weight fp32 -> bf16 conversion
// ---------------------------------------------------------------------------
__global__ void convert_kernel(const float* __restrict__ src,
                               unsigned short* __restrict__ dst, int n4) {
    int gid = blockIdx.x * 256 + threadIdx.x;
    if (gid >= n4) return;
    int idx = gid * 4;
    float4 v = *(const float4*)(src + idx);
    ushort4 r = make_ushort4(f2bf(v.x), f2bf(v.y), f2bf(v.z), f2bf(v.w));
    *(ushort4*)(dst + idx) = r;
}

__global__ void convertw_kernel(const float* __restrict__ wq,
                                const float* __restrict__ wo,
                                const float* __restrict__ wf,
                                const float* __restrict__ wp,
                                unsigned short* __restrict__ dst) {
    int idx = (blockIdx.x * 256 + threadIdx.x) * 4;
    const float* s; int off;
    if (idx < WQ_SZ)                     { s = wq; off = idx; }
    else if (idx < WQ_SZ + WO_SZ)        { s = wo; off = idx - WQ_SZ; }
    else if (idx < WQ_SZ + WO_SZ + WF_SZ){ s = wf; off = idx - WQ_SZ - WO_SZ; }
    else                                 { s = wp; off = idx - WQ_SZ - WO_SZ - WF_SZ; }
    float4 v = *(const float4*)(s + off);
    ushort4 r = make_ushort4(f2bf(v.x), f2bf(v.y), f2bf(v.z), f2bf(v.w));
    *(ushort4*)(dst + idx) = r;
}

// ---------------------------------------------------------------------------
// im2col + normalize -> bf16 patches [6272, 768]
// ---------------------------------------------------------------------------
__global__ void im2col_kernel(const float* __restrict__ img,
                              unsigned short* __restrict__ out) {
    int idx = blockIdx.x * 256 + threadIdx.x;
    int col = idx % 768;
    int row = idx / 768;
    int b = row / NPATCH, p = row % NPATCH;
    int ph = p / 14, pw = p % 14;
    int c  = col >> 8;
    int r  = col & 255;
    int kh = r >> 4, kw = r & 15;
    int y = ph * 16 + kh, x = pw * 16 + kw;
    const float mean[3] = {0.48145466f, 0.4578275f, 0.40821073f};
    const float stdv[3] = {0.26862954f, 0.26130258f, 0.27577711f};
    float v = img[((size_t)(b * 3 + c) * 224 + y) * 224 + x];
    out[idx] = f2bf((v - mean[c]) / stdv[c]);
}

// ---------------------------------------------------------------------------
// MFMA bf16 GEMM: C[m,n] = sum_k A[m,k]*W[n,k] (+bias) (+res fp32) (QuickGELU)
// v11: unified template <ODT, ACT, BM, BN>, BK=64.
//  BM=256 -> 8 waves / 512 thr (r7/r9-verified v10 geometry, 128 KB LDS).
//  BM=128 -> 4 waves / 256 thr (r5-verified v6 geometry, 64 KB LDS,
//            2 blocks/CU -> 2x resident waves -> higher per-CU ingest).
//  Law (r0-r9): per-CU ingest scales with resident waves issuing loads;
//  big tiles halve staged bytes but also halve residency (wash). Per-GEMM
//  best-measured: qkv/fc/conv 256^2 z1; proj 128^2 z2 600blk (89us, r5);
//  out 128^2 z1 plain+res.
//  - staging/read XOR swizzle verbatim (SQ_LDS_BANK_CONFLICT=0, r3/r5/r7)
//  - 2-phase dbuf + __syncthreads
//  - ODT==2: fp32 atomicAdd into C (pre-holds residual; bias at z==0 only)
//  - XCD-aware bijective remap
// ---------------------------------------------------------------------------
template<int ODT, int ACT, int BM, int BN>
__global__ __launch_bounds__((BM == 128) ? 256 : 512) void gemm_mfma(
        const unsigned short* __restrict__ A, const unsigned short* __restrict__ W,
        const float* __restrict__ bias, const float* __restrict__ res,
        void* __restrict__ Cv, int M, int N, int K)
{
    constexpr int WAVES = (BM == 128) ? 4 : 8;
    constexpr int WN = (BN == 256) ? 4 : 2;        // waves along N
    constexpr int WM = WAVES / WN;                 // waves along M
    constexpr int MI = BM / WM / 16;               // A-fragments per wave
    constexpr int NI = BN / WN / 16;               // W-fragments per wave
    constexpr int NAI = BM / (WAVES * 8);          // A stage instrs per wave
    constexpr int NWI = BN / (WAVES * 8);          // W stage instrs per wave
    constexpr int RS  = WAVES * 8;                 // row stride between instrs

    __shared__ unsigned short As[2][BM * 64];
    __shared__ unsigned short Ws[2][BN * 64];
    const int tid = threadIdx.x;
    const int w = tid >> 6, l = tid & 63;

    // ---- XCD-aware bijective remap of linear workgroup id (T1, m204) ----
    const int gx = gridDim.x;
    const int wg  = blockIdx.y * gx + blockIdx.x;
    const int nwg = gx * gridDim.y;
    const int q = nwg >> 3, r8 = nwg & 7;
    const int xcd = wg & 7, lo = wg >> 3;
    const int swz = (xcd < r8 ? xcd * (q + 1) : r8 * (q + 1) + (xcd - r8) * q) + lo;
    const int m0 = (swz / gx) * BM;
    const int n0 = (swz % gx) * BN;

    // ---- split-K ----
    const int kseg  = K / gridDim.z;
    const int kbase = blockIdx.z * kseg;

    // ---- staging (r3/r5-verified): pre-swizzled global src, linear LDS ----
    // per instr: 64 lanes x 16B = 1 KB = 8 rows x 64 cols(bf16).
    // lane l -> row l>>3, src 16B-chunk (l&7)^(l>>3); wave w instr i covers
    // rows [w*8 + i*RS, +8).
    const int lrow = l >> 3;
    const int lchk = (l & 7) ^ lrow;
    const unsigned short* agp = A + (size_t)(m0 + w * 8 + lrow) * K + kbase + lchk * 8;
    const unsigned short* wgp = W + (size_t)(n0 + w * 8 + lrow) * K + kbase + lchk * 8;
    const int lbase = (w * 8) * 64;      // shorts; + i*RS*64 per instr

    // ---- fragment read offsets (swizzled; verified pattern) ----
    const int wm = w / WN, wn = w % WN;
    const int fr = l & 15, fq = l >> 4;
    int aoff[2][MI], woff[2][NI];
    #pragma unroll
    for (int ks = 0; ks < 2; ks++) {
        const int pc = ((ks * 4 + fq) ^ (fr & 7)) * 8;
        #pragma unroll
        for (int i = 0; i < MI; i++)
            aoff[ks][i] = (wm * (MI * 16) + i * 16 + fr) * 64 + pc;
        #pragma unroll
        for (int j = 0; j < NI; j++)
            woff[ks][j] = (wn * (NI * 16) + j * 16 + fr) * 64 + pc;
    }

    f32x4 acc[MI][NI] = {};
    const int nt = kseg >> 6;   // BK=64

    #define STAGE(t, bf) do {                                              \
        const int _ko = (t) << 6;                                          \
        _Pragma("unroll")                                                  \
        for (int _i = 0; _i < NAI; _i++)                                   \
            async_ld16(agp + (size_t)_i * RS * K + _ko,                    \
                       &As[bf][lbase + _i * RS * 64]);                     \
        _Pragma("unroll")                                                  \
        for (int _i = 0; _i < NWI; _i++)                                   \
            async_ld16(wgp + (size_t)_i * RS * K + _ko,                    \
                       &Ws[bf][lbase + _i * RS * 64]);                     \
    } while (0)

    auto compute = [&](const unsigned short* ab, const unsigned short* wb) {
        #pragma unroll
        for (int ks = 0; ks < 2; ks++) {
            bf16x8 wf[NI];
            #pragma unroll
            for (int j = 0; j < NI; j++)
                wf[j] = *(const bf16x8*)(wb + woff[ks][j]);
            #pragma unroll
            for (int i = 0; i < MI; i++) {
                bf16x8 af = *(const bf16x8*)(ab + aoff[ks][i]);
                #pragma unroll
                for (int j = 0; j < NI; j++) {
                    acc[i][j] = __builtin_amdgcn_mfma_f32_16x16x32_bf16(
                        af, wf[j], acc[i][j], 0, 0, 0);
                }
            }
        }
    };

    // prologue
    STAGE(0, 0);
    __syncthreads();

    int bf = 0;
    for (int t = 0; t < nt; t++) {
        if (t + 1 < nt) STAGE(t + 1, bf ^ 1);
        compute(As[bf], Ws[bf]);
        __syncthreads();        // staged t+1 landed; all reads of bf consumed
        bf ^= 1;
    }
    #undef STAGE

    const bool addb = (ODT != 2) || (blockIdx.z == 0);
    float bn[NI];
    #pragma unroll
    for (int j = 0; j < NI; j++)
        bn[j] = (bias && addb) ? bias[n0 + wn * (NI * 16) + j * 16 + fr] : 0.f;

    #pragma unroll
    for (int i = 0; i < MI; i++) {
        #pragma unroll
        for (int r = 0; r < 4; r++) {
            int m = m0 + wm * (MI * 16) + i * 16 + fq * 4 + r;
            if (m < M) {
                size_t rowb = (size_t)m * N;
                #pragma unroll
                for (int j = 0; j < NI; j++) {
                    int n = n0 + wn * (NI * 16) + j * 16 + fr;
                    float v = acc[i][j][r] + bn[j];
                    if (ODT == 2) {
                        atomicAdd((float*)Cv + rowb + n, v);
                    } else {
                        if (res) v += res[rowb + n];
                        if (ACT) v = v / (1.f + __expf(-1.702f * v));
                        if (ODT == 0) ((float*)Cv)[rowb + n] = v;
                        else ((unsigned short*)Cv)[rowb + n] = f2bf(v);
                    }
                }
            }
        }
    }
}

// ---------------------------------------------------------------------------
// LayerNorm fp32 in -> bf16 out. One block per token.
// ---------------------------------------------------------------------------
__global__ void ln_kernel(const float* __restrict__ in, unsigned short* __restrict__ out,
                          const float* __restrict__ s, const float* __restrict__ b) {
    int t = blockIdx.x;
    const float* row = in + (size_t)t * Dv;
    int tid = threadIdx.x;
    float v[3], s1 = 0.f, s2 = 0.f;
    #pragma unroll
    for (int i = 0; i < 3; i++) {
        v[i] = row[tid + 256 * i];
        s1 += v[i]; s2 += v[i] * v[i];
    }
    reduce2_256(s1, s2);
    float mean = s1 * (1.0f / Dv);
    float var  = s2 * (1.0f / Dv) - mean * mean;
    float rstd = rsqrtf(var + 1e-5f);
    unsigned short* orow = out + (size_t)t * Dv;
    #pragma unroll
    for (int i = 0; i < 3; i++) {
        int d = tid + 256 * i;
        orow[d] = f2bf((v[i] - mean) * rstd * s[d] + b[d]);
    }
}

// ---------------------------------------------------------------------------
// embed (cls/patch + pos) + ln_pre -> x fp32. One block per token.
// ---------------------------------------------------------------------------
__global__ void embed_ln_kernel(const float* __restrict__ conv_out,
                                const float* __restrict__ cls,
                                const float* __restrict__ pos,
                                const float* __restrict__ s,
                                const float* __restrict__ b,
                                float* __restrict__ x) {
    int t = blockIdx.x;
    int bb = t / Sv, si = t % Sv;
    int tid = threadIdx.x;
    float v[3], s1 = 0.f, s2 = 0.f;
    #pragma unroll
    for (int i = 0; i < 3; i++) {
        int d = tid + 256 * i;
        float e = (si == 0) ? cls[d]
                            : conv_out[((size_t)bb * NPATCH + (si - 1)) * Dv + d];
        v[i] = e + pos[(size_t)si * Dv + d];
        s1 += v[i]; s2 += v[i] * v[i];
    }
    reduce2_256(s1, s2);
    float mean = s1 * (1.0f / Dv);
    float var  = s2 * (1.0f / Dv) - mean * mean;
    float rstd = rsqrtf(var + 1e-5f);
    float* orow = x + (size_t)t * Dv;
    #pragma unroll
    for (int i = 0; i < 3; i++) {
        int d = tid + 256 * i;
        orow[d] = (v[i] - mean) * rstd * s[d] + b[d];
    }
}

// ---------------------------------------------------------------------------
// Attention v4 (MFMA): grid (7, H, B); block = 256 thr = 4 waves; 32 q-rows.
// ---------------------------------------------------------------------------
__global__ __launch_bounds__(256) void attn4_kernel(
        const unsigned short* __restrict__ qkv, unsigned short* __restrict__ o) {
    const int qg = blockIdx.x, h = blockIdx.y, b = blockIdx.z;
    __shared__ __align__(16) unsigned short vt[64][232];   // V^T [d][j], 29.7 KB
    __shared__ __align__(16) unsigned short pb[32][236];   // P bf16 [row][k], 14.8 KB
    __shared__ float red[4][32];
    __shared__ float smax_f[32];
    __shared__ float sinv_f[32];

    const int tid = threadIdx.x;
    const int w = tid >> 6, l = tid & 63;
    const int fr = l & 15, fq = l >> 4;
    const size_t base = (size_t)b * Sv;
    const unsigned int* q32 = (const unsigned int*)qkv;    // row stride 1152 uints

    // ---- stage V^T (cols >= 197 zeroed) ----
    for (int i = tid; i < 224 * 32; i += 256) {
        int j = i >> 5, u = i & 31;
        unsigned int val = (j < Sv) ? q32[(base + j) * 1152 + 768 + h * 32 + u] : 0u;
        vt[2 * u][j]     = (unsigned short)(val & 0xffffu);
        vt[2 * u + 1][j] = (unsigned short)(val >> 16);
    }

    union U { uint4 u; bf16x8 v; };

    // ---- QK^T: sc[mt][s], rows qg*32+mt*16+fq*4+r, cols (w+4s)*16+fr ----
    f32x4 sc[2][4] = {};
    #pragma unroll
    for (int ks = 0; ks < 2; ks++) {
        U aq[2];
        #pragma unroll
        for (int mt = 0; mt < 2; mt++) {
            int row = qg * 32 + mt * 16 + fr;
            int rc = row < Sv ? row : Sv - 1;
            aq[mt].u = *(const uint4*)(qkv + (base + rc) * 2304 + h * 64 + ks * 32 + fq * 8);
        }
        #pragma unroll
        for (int s = 0; s < 4; s++) {
            int nt = w + 4 * s;
            if (nt >= 14) continue;
            int col = nt * 16 + fr;
            int cc = col < Sv ? col : Sv - 1;
            U bq;
            bq.u = *(const uint4*)(qkv + (base + cc) * 2304 + 768 + h * 64 + ks * 32 + fq * 8);
            #pragma unroll
            for (int mt = 0; mt < 2; mt++)
                sc[mt][s] = __builtin_amdgcn_mfma_f32_16x16x32_bf16(
                    aq[mt].v, bq.v, sc[mt][s], 0, 0, 0);
        }
    }

    // ---- scale + mask + row max ----
    float rmax[2][4];
    #pragma unroll
    for (int mt = 0; mt < 2; mt++)
        #pragma unroll
        for (int r = 0; r < 4; r++) rmax[mt][r] = -1e30f;
    #pragma unroll
    for (int mt = 0; mt < 2; mt++) {
        #pragma unroll
        for (int s = 0; s < 4; s++) {
            int nt = w + 4 * s;
            int col = nt * 16 + fr;
            bool valid = (nt < 14) && (col < Sv);
            #pragma unroll
            for (int r = 0; r < 4; r++) {
                float v = valid ? sc[mt][s][r] * 0.125f : -1e30f;
                sc[mt][s][r] = v;
                rmax[mt][r] = fmaxf(rmax[mt][r], v);
            }
        }
    }
    #pragma unroll
    for (int mt = 0; mt < 2; mt++) {
        #pragma unroll
        for (int r = 0; r < 4; r++) {
            float m = rmax[mt][r];
            m = fmaxf(m, __shfl_xor(m, 1, 64));
            m = fmaxf(m, __shfl_xor(m, 2, 64));
            m = fmaxf(m, __shfl_xor(m, 4, 64));
            m = fmaxf(m, __shfl_xor(m, 8, 64));
            rmax[mt][r] = m;
        }
    }
    if (fr == 0) {
        #pragma unroll
        for (int mt = 0; mt < 2; mt++)
            #pragma unroll
            for (int r = 0; r < 4; r++)
                red[w][mt * 16 + fq * 4 + r] = rmax[mt][r];
    }
    __syncthreads();
    if (tid < 32)
        smax_f[tid] = fmaxf(fmaxf(red[0][tid], red[1][tid]),
                            fmaxf(red[2][tid], red[3][tid]));
    __syncthreads();

    // ---- exp + row sum + write P (bf16, A layout) ----
    float rsum[2][4] = {};
    #pragma unroll
    for (int mt = 0; mt < 2; mt++) {
        float fm[4];
        #pragma unroll
        for (int r = 0; r < 4; r++) fm[r] = smax_f[mt * 16 + fq * 4 + r];
        #pragma unroll
        for (int s = 0; s < 4; s++) {
            int nt = w + 4 * s;
            if (nt >= 14) continue;
            int col = nt * 16 + fr;
            #pragma unroll
            for (int r = 0; r < 4; r++) {
                float p = (col < Sv) ? __expf(sc[mt][s][r] - fm[r]) : 0.f;
                rsum[mt][r] += p;
                pb[mt * 16 + fq * 4 + r][col] = f2bf(p);
            }
        }
    }
    #pragma unroll
    for (int mt = 0; mt < 2; mt++) {
        #pragma unroll
        for (int r = 0; r < 4; r++) {
            float s = rsum[mt][r];
            s += __shfl_xor(s, 1, 64);
            s += __shfl_xor(s, 2, 64);
            s += __shfl_xor(s, 4, 64);
            s += __shfl_xor(s, 8, 64);
            rsum[mt][r] = s;
        }
    }
    if (fr == 0) {
        #pragma unroll
        for (int mt = 0; mt < 2; mt++)
            #pragma unroll
            for (int r = 0; r < 4; r++)
                red[w][mt * 16 + fq * 4 + r] = rsum[mt][r];
    }
    __syncthreads();
    if (tid < 32)
        sinv_f[tid] = 1.f / (red[0][tid] + red[1][tid] + red[2][tid] + red[3][tid]);
    __syncthreads();   // also guarantees vt + pb staging complete

    // ---- PV: wave w -> output dims [w*16, w*16+16) ----
    f32x4 oc[2] = {};
    #pragma unroll
    for (int ks = 0; ks < 7; ks++) {
        U bv;
        bv.u = *(const uint4*)&vt[w * 16 + fr][ks * 32 + fq * 8];
        #pragma unroll
        for (int mt = 0; mt < 2; mt++) {
            const unsigned short* ap = &pb[mt * 16 + fr][ks * 32 + fq * 8];
            uint2 lo = *(const uint2*)ap;
            uint2 hi = *(const uint2*)(ap + 4);
            U a; a.u = make_uint4(lo.x, lo.y, hi.x, hi.y);
            oc[mt] = __builtin_amdgcn_mfma_f32_16x16x32_bf16(a.v, bv.v, oc[mt], 0, 0, 0);
        }
    }

    // ---- epilogue: /= rowsum, store bf16 ----
    #pragma unroll
    for (int mt = 0; mt < 2; mt++) {
        #pragma unroll
        for (int r = 0; r < 4; r++) {
            int lrow = mt * 16 + fq * 4 + r;
            int row = qg * 32 + lrow;
            if (row < Sv)
                o[(base + row) * Dv + h * 64 + w * 16 + fr] =
                    f2bf(oc[mt][r] * sinv_f[lrow]);
        }
    }
}

// ---------------------------------------------------------------------------
// Head: ln_post on cls token + @ vis_proj [768,512] fp32. One block per batch.
// ---------------------------------------------------------------------------
__global__ void head_kernel(const float* __restrict__ x,
                            const float* __restrict__ s, const float* __restrict__ b,
                            const float* __restrict__ vp, float* __restrict__ out) {
    int bb = blockIdx.x, tid = threadIdx.x;
    __shared__ float xn[Dv];
    const float* row = x + (size_t)(bb * Sv) * Dv;
    float v[3], s1 = 0.f, s2 = 0.f;
    #pragma unroll
    for (int i = 0; i < 3; i++) {
        v[i] = row[tid + 256 * i];
        s1 += v[i]; s2 += v[i] * v[i];
    }
    reduce2_256(s1, s2);
    float mean = s1 * (1.0f / Dv);
    float var  = s2 * (1.0f / Dv) - mean * mean;
    float rstd = rsqrtf(var + 1e-5f);
    #pragma unroll
    for (int i = 0; i < 3; i++) {
        int d = tid + 256 * i;
        xn[d] = (v[i] - mean) * rstd * s[d] + b[d];
    }
    __syncthreads();
    float acc0 = 0.f, acc1 = 0.f;
    for (int d = 0; d < Dv; d++) {
        float xv = xn[d];
        acc0 += xv * vp[(size_t)d * Ov + tid];
        acc1 += xv * vp[(size_t)d * Ov + tid + 256];
    }
    out[(size_t)bb * Ov + tid]       = acc0;
    out[(size_t)bb * Ov + tid + 256] = acc1;
}

// ---------------------------------------------------------------------------
extern "C" void kernel_launch(void* const* d_in, const int* in_sizes, int n_in,
                              void* d_out, int out_size, void* d_ws, size_t ws_size,
                              hipStream_t stream) {
    const float* images   = (const float*)d_in[0];
    const float* conv_w   = (const float*)d_in[1];
    const float* cls_emb  = (const float*)d_in[2];
    const float* pos_emb  = (const float*)d_in[3];
    const float* lnpre_s  = (const float*)d_in[4];
    const float* lnpre_b  = (const float*)d_in[5];
    const float* ln1_s    = (const float*)d_in[6];
    const float* ln1_b    = (const float*)d_in[7];
    const float* qkv_w    = (const float*)d_in[8];
    const float* qkv_b    = (const float*)d_in[9];
    const float* out_w    = (const float*)d_in[10];
    const float* out_b    = (const float*)d_in[11];
    const float* ln2_s    = (const float*)d_in[12];
    const float* ln2_b    = (const float*)d_in[13];
    const float* fc_w     = (const float*)d_in[14];
    const float* fc_b     = (const float*)d_in[15];
    const float* proj_w   = (const float*)d_in[16];
    const float* proj_b   = (const float*)d_in[17];
    const float* lnpost_s = (const float*)d_in[18];
    const float* lnpost_b = (const float*)d_in[19];
    const float* vis_proj = (const float*)d_in[20];
    float* out = (float*)d_out;

    char* p = (char*)d_ws;
    float* x              = (float*)p;          p += (size_t)TOK * Dv * 4;       // 19.4 MB
    unsigned short* abuf  = (unsigned short*)p; p += (size_t)MPAD * Dv * 2;      //  9.8 MB
    unsigned short* qkvb  = (unsigned short*)p; p += (size_t)MPAD * 2304 * 2;    // 29.5 MB
    unsigned short* hbuf  = (unsigned short*)p; p += (size_t)MPAD * Fv * 2;      // 39.3 MB
    unsigned short* wbuf  = (unsigned short*)p; p += (size_t)WTOT * 2;           // 14.2 MB
    unsigned short* cwb   = (unsigned short*)p; p += (size_t)WO_SZ * 2;          //  1.2 MB
    // aliases (pre-loop only):
    unsigned short* im2c  = qkvb;               // [6272,768] bf16 (rows to 6400 readable)
    float* convo          = (float*)hbuf;       // [6272,768] fp32

    // patch embedding
    convert_kernel<<<WO_SZ / 4 / 256, 256, 0, stream>>>(conv_w, cwb, WO_SZ / 4);
    im2col_kernel<<<(CONV_M * Dv) / 256, 256, 0, stream>>>(images, im2c);
    gemm_mfma<0, 0, 256, 256><<<dim3(Dv / 256, MPAD / 256, 1), 512, 0, stream>>>(
        im2c, cwb, nullptr, nullptr, convo, CONV_M, Dv, Dv);
    embed_ln_kernel<<<TOK, 256, 0, stream>>>(convo, cls_emb, pos_emb,
                                             lnpre_s, lnpre_b, x);

    unsigned short* wq = wbuf;
    unsigned short* wo = wbuf + WQ_SZ;
    unsigned short* wf = wbuf + WQ_SZ + WO_SZ;
    unsigned short* wp = wbuf + WQ_SZ + WO_SZ + WF_SZ;

    for (int l = 0; l < Lv; l++) {
        convertw_kernel<<<WTOT / 4 / 256, 256, 0, stream>>>(
            qkv_w + (size_t)l * WQ_SZ, out_w + (size_t)l * WO_SZ,
            fc_w + (size_t)l * WF_SZ, proj_w + (size_t)l * WP_SZ, wbuf);
        ln_kernel<<<TOK, 256, 0, stream>>>(x, abuf, ln1_s + l * Dv, ln1_b + l * Dv);
        // qkv: 256x256, z=1 (225 blocks, one round)
        gemm_mfma<1, 0, 256, 256><<<dim3(2304 / 256, MPAD / 256, 1), 512, 0, stream>>>(
            abuf, wq, qkv_b + (size_t)l * 2304, nullptr, qkvb, TOK, 2304, Dv);
        attn4_kernel<<<dim3(7, Hh, Bv), 256, 0, stream>>>(qkvb, abuf);
        // out_proj: 128x128, z=1, 300 blocks, 2 blk/CU, plain store + residual
        gemm_mfma<0, 0, 128, 128><<<dim3(Dv / 128, MPAD / 128, 1), 256, 0, stream>>>(
            abuf, wo, out_b + (size_t)l * Dv, x, x, TOK, Dv, Dv);
        ln_kernel<<<TOK, 256, 0, stream>>>(x, abuf, ln2_s + l * Dv, ln2_b + l * Dv);
        // fc: 256x256, z=1
        gemm_mfma<1, 1, 256, 256><<<dim3(Fv / 256, MPAD / 256, 1), 512, 0, stream>>>(
            abuf, wf, fc_b + (size_t)l * Fv, nullptr, hbuf, TOK, Fv, Dv);
        // mlp proj: 128x128, z=2, 600 blocks, 2 blk/CU (r5-measured 89us)
        gemm_mfma<2, 0, 128, 128><<<dim3(Dv / 128, MPAD / 128, 2), 256, 0, stream>>>(
            hbuf, wp, proj_b + (size_t)l * Dv, nullptr, x, TOK, Dv, Fv);
    }

    head_kernel<<<Bv, 256, 0, stream>>>(x, lnpost_s, lnpost_b, vis_proj, out);
}